// Round 2
// baseline (7932.620 us; speedup 1.0000x reference)
//
#include <hip/hip_runtime.h>
#include <math.h>

#define NPTS 8192
#define KNNK 10

__device__ __forceinline__ float preluf(float v, float a){ return v >= 0.f ? v : a*v; }
__device__ __forceinline__ float4 f4fma(float a, float4 b, float4 c){
  return make_float4(fmaf(a,b.x,c.x), fmaf(a,b.y,c.y), fmaf(a,b.z,c.z), fmaf(a,b.w,c.w));
}
__device__ __forceinline__ bool lexless(float d1, int i1, float d2, int i2){
  return (d1 < d2) || (d1 == d2 && i1 < i2);
}

// ---------- prep: x0pad (targets padded to 4ch) + sqnorm ----------
__global__ __launch_bounds__(256) void prep0_kernel(const float* __restrict__ T,
                                                    float* __restrict__ x0,
                                                    float* __restrict__ sqn){
  int p = blockIdx.x*256 + threadIdx.x;
  float t0 = T[p*3+0], t1 = T[p*3+1], t2 = T[p*3+2];
  *(float4*)(x0 + (size_t)p*4) = make_float4(t0,t1,t2,0.f);
  float s = fmaf(t0,t0,0.f); s = fmaf(t1,t1,s); s = fmaf(t2,t2,s); s = fmaf(0.f,0.f,s);
  sqn[p] = s;
}

__global__ __launch_bounds__(256) void sqnorm_kernel(const float* __restrict__ XC, int cin,
                                                     float* __restrict__ sqn){
  int p = blockIdx.x*256 + threadIdx.x;
  const float4* r = (const float4*)(XC + (size_t)p*192 + cin);
  float s = 0.f;
  #pragma unroll
  for (int c4=0;c4<16;++c4){
    float4 v = r[c4];
    s = fmaf(v.x,v.x,s); s = fmaf(v.y,v.y,s); s = fmaf(v.z,v.z,s); s = fmaf(v.w,v.w,s);
  }
  sqn[p] = s;
}

// ---------- fused distance-GEMM + top-10 KNN ----------
// block: 512 thr (8 waves -> 2/SIMD), 128 queries, j-tile 256, thread tile 8x8.
// xqT2: c-pair interleaved (conflict-free A reads). uni: xjT / dch / merge union.
// topk: per-thread top-10 over fixed j-quarter, 2-stage lex merge.
template<int C>
__global__ __launch_bounds__(512) void knn_kernel(const float* __restrict__ X, int ldx, int coff,
                                                  const float* __restrict__ sqn,
                                                  int* __restrict__ idxout){
  constexpr int CP = C/2;
  __shared__ __align__(16) float xqT2[CP*256];
  __shared__ __align__(16) float uni[16896];   // xjT[C][260] | dch[128][132] | merge lists
  __shared__ float s_x2q[128];
  __shared__ float s_x2j[256];

  const int b   = blockIdx.y;
  const int q0  = blockIdx.x * 128;
  const int tid = threadIdx.x;
  const int tm  = tid & 15;     // q-group (8 q each)
  const int tn  = tid >> 4;     // j-group 0..31 (8 j each)
  const int tq  = tid & 127;    // scan: query
  const int th  = tid >> 7;     // scan: quarter 0..3

  const float* Xb = X + (size_t)b * NPTS * ldx + coff;

  // stage xq (once): c-pair interleaved layout xqT2[c/2][q*2 + (c&1)]
  for (int i = tid; i < 128*(C/4); i += 512) {
    int r = i / (C/4), c4 = (i % (C/4))*4;
    float4 v = *(const float4*)(Xb + (size_t)(q0+r)*ldx + c4);
    float c0v[4] = {v.x, v.y, v.z, v.w};
    #pragma unroll
    for (int j=0;j<4;++j){
      int c = c4 + j;
      xqT2[(c>>1)*256 + r*2 + (c&1)] = c0v[j];
    }
  }
  if (tid < 128) s_x2q[tid] = sqn[b*NPTS + q0 + tid];

  float bd[10]; int bi[10];
  #pragma unroll
  for (int u=0;u<10;++u){ bd[u] = INFINITY; bi[u] = 0x7fffffff; }

  for (int j0 = 0; j0 < NPTS; j0 += 256) {
    __syncthreads();  // (A) prev scan done; xq staged (first iter)
    for (int i = tid; i < 256*(C/4); i += 512) {
      int r = i / (C/4), c4 = (i % (C/4))*4;
      float4 v = *(const float4*)(Xb + (size_t)(j0+r)*ldx + c4);
      uni[(c4+0)*260 + r] = v.x;
      uni[(c4+1)*260 + r] = v.y;
      uni[(c4+2)*260 + r] = v.z;
      uni[(c4+3)*260 + r] = v.w;
    }
    if (tid < 256) s_x2j[tid] = sqn[b*NPTS + j0 + tid];
    __syncthreads();  // (B) staging done

    float acc[8][8];
    #pragma unroll
    for (int i=0;i<8;++i)
      #pragma unroll
      for (int j=0;j<8;++j) acc[i][j] = 0.f;

    #pragma unroll
    for (int c2=0; c2<CP; ++c2) {
      float aq[16], b0[8], b1[8];
      *(float4*)&aq[0]  = *(const float4*)&xqT2[c2*256 + tm*16 + 0];
      *(float4*)&aq[4]  = *(const float4*)&xqT2[c2*256 + tm*16 + 4];
      *(float4*)&aq[8]  = *(const float4*)&xqT2[c2*256 + tm*16 + 8];
      *(float4*)&aq[12] = *(const float4*)&xqT2[c2*256 + tm*16 + 12];
      *(float4*)&b0[0]  = *(const float4*)&uni[(2*c2+0)*260 + tn*8 + 0];
      *(float4*)&b0[4]  = *(const float4*)&uni[(2*c2+0)*260 + tn*8 + 4];
      *(float4*)&b1[0]  = *(const float4*)&uni[(2*c2+1)*260 + tn*8 + 0];
      *(float4*)&b1[4]  = *(const float4*)&uni[(2*c2+1)*260 + tn*8 + 4];
      #pragma unroll
      for (int i=0;i<8;++i)
        #pragma unroll
        for (int j=0;j<8;++j) {
          acc[i][j] = fmaf(aq[2*i+0], b0[j], acc[i][j]);
          acc[i][j] = fmaf(aq[2*i+1], b1[j], acc[i][j]);
        }
    }
    __syncthreads();  // (C) gemm reads done; uni becomes dch[128][132]

    #pragma unroll
    for (int ch=0; ch<2; ++ch) {
      if ((tn>>4) == ch) {
        const int tn2 = tn & 15;
        #pragma unroll
        for (int qi=0;qi<8;++qi) {
          const int row = tm*8+qi;
          const float xq2 = s_x2q[row];
          #pragma unroll
          for (int jq=0;jq<2;++jq) {
            const int jr = (jq + tm) & 1;        // bank rotation
            const int jl = tn2*8 + jr*4;         // col within 128-chunk
            const int jg = ch*128 + jl;          // col within 256-tile
            float4 v;
            v.x = xq2 + s_x2j[jg+0] - 2.f*acc[qi][jr*4+0];
            v.y = xq2 + s_x2j[jg+1] - 2.f*acc[qi][jr*4+1];
            v.z = xq2 + s_x2j[jg+2] - 2.f*acc[qi][jr*4+2];
            v.w = xq2 + s_x2j[jg+3] - 2.f*acc[qi][jr*4+3];
            *(float4*)&uni[row*132 + jl] = v;
          }
        }
      }
      __syncthreads();  // (D/F) dch written
      {
        const int jbase = j0 + ch*128 + th*32;
        #pragma unroll
        for (int r4=0;r4<8;++r4) {
          float4 dv = *(const float4*)&uni[tq*132 + th*32 + r4*4];
          float dd[4] = {dv.x, dv.y, dv.z, dv.w};
          #pragma unroll
          for (int u=0;u<4;++u) {
            float d = dd[u]; int jj = jbase + r4*4 + u;
            if (lexless(d, jj, bd[9], bi[9])) {
              bd[9] = d; bi[9] = jj;
              #pragma unroll
              for (int s=8;s>=0;--s) {
                if (lexless(bd[s+1], bi[s+1], bd[s], bi[s])) {
                  float td = bd[s]; bd[s] = bd[s+1]; bd[s+1] = td;
                  int ti = bi[s]; bi[s] = bi[s+1]; bi[s+1] = ti;
                }
              }
            }
          }
        }
      }
      __syncthreads();  // (E) scan done
    }
  }

  // ---- final merge: 4 partial lists per query ----
  // lists at cols th*20 (d) / th*20+10 (idx-bits)
  #pragma unroll
  for (int u=0;u<10;++u) {
    uni[tq*132 + th*20 + u]      = bd[u];
    uni[tq*132 + th*20 + 10 + u] = __int_as_float(bi[u]);
  }
  __syncthreads();
  if (tid < 256) {   // stage 1: merge (0,1) and (2,3) -> cols 80+hf*20
    float* row = &uni[(tid & 127)*132];
    const int hf = tid >> 7;
    const float* La = row + hf*40;
    const float* Lb = row + hf*40 + 20;
    float* Od = row + 80 + hf*20;
    int ia=0, ib=0;
    #pragma unroll
    for (int u=0;u<10;++u) {
      float da = La[ia], db = Lb[ib];
      int ja = __float_as_int(La[10+ia]), jb = __float_as_int(Lb[10+ib]);
      bool ta = lexless(da, ja, db, jb);
      Od[u]    = ta ? da : db;
      Od[10+u] = ta ? La[10+ia] : Lb[10+ib];
      ia += ta ? 1 : 0; ib += ta ? 0 : 1;
    }
  }
  __syncthreads();
  if (tid < 128) {   // stage 2
    const float* row = &uni[tid*132];
    int ia=0, ib=0;
    int res[10];
    #pragma unroll
    for (int u=0;u<10;++u) {
      float da = row[80+ia], db = row[100+ib];
      int ja = __float_as_int(row[90+ia]), jb = __float_as_int(row[110+ib]);
      bool ta = lexless(da, ja, db, jb);
      res[u] = ta ? ja : jb;
      ia += ta ? 1 : 0; ib += ta ? 0 : 1;
    }
    int* op = idxout + ((size_t)b*NPTS + q0 + tid)*KNNK;
    #pragma unroll
    for (int u=0;u<10;++u) op[u] = res[u];
  }
}

// ---------- prep U/D for 64-ch edge conv: U = X@W[0:64], D = X@(W[64:128]-W[0:64]) ----------
__global__ __launch_bounds__(256) void prepUD64_kernel(const float* __restrict__ XC, int cin,
                                                       const float* __restrict__ W,
                                                       float* __restrict__ U,
                                                       float* __restrict__ D){
  int p = blockIdx.x*256 + threadIdx.x;
  float x[64];
  {
    const float4* xr = (const float4*)(XC + (size_t)p*192 + cin);
    #pragma unroll
    for (int c4=0;c4<16;++c4){
      float4 v = xr[c4];
      x[c4*4]=v.x; x[c4*4+1]=v.y; x[c4*4+2]=v.z; x[c4*4+3]=v.w;
    }
  }
  const float4* W4 = (const float4*)W;
  float4 z[16];
  #pragma unroll
  for (int o=0;o<16;++o) z[o] = make_float4(0,0,0,0);
  #pragma unroll
  for (int c=0;c<64;++c) {
    const float xc = x[c];
    #pragma unroll
    for (int o=0;o<16;++o) z[o] = f4fma(xc, W4[c*16+o], z[o]);
  }
  float4* up = (float4*)(U + (size_t)p*64);
  #pragma unroll
  for (int o=0;o<16;++o) up[o] = z[o];
  #pragma unroll
  for (int o=0;o<16;++o) z[o] = make_float4(0,0,0,0);
  #pragma unroll
  for (int c=0;c<64;++c) {
    const float xc = x[c];
    #pragma unroll
    for (int o=0;o<16;++o) {
      float4 wt = W4[c*16+o], wb = W4[(64+c)*16+o];
      float4 wd = make_float4(wb.x-wt.x, wb.y-wt.y, wb.z-wt.z, wb.w-wt.w);
      z[o] = f4fma(xc, wd, z[o]);
    }
  }
  float4* dp = (float4*)(D + (size_t)p*64);
  #pragma unroll
  for (int o=0;o<16;++o) dp[o] = z[o];
}

// ---------- prep U/D for conv1 (targets, 12-ch edge feats collapse to 3) ----------
__global__ __launch_bounds__(256) void prepUD12_kernel(const float* __restrict__ T,
                                                       const float* __restrict__ W1,
                                                       float* __restrict__ U,
                                                       float* __restrict__ D){
  int p = blockIdx.x*256 + threadIdx.x;
  float t[3] = {T[p*3+0], T[p*3+1], T[p*3+2]};
  const float4* W = (const float4*)W1;
  float4 u[16], q[16];
  #pragma unroll
  for (int o=0;o<16;++o){ u[o]=make_float4(0,0,0,0); q[o]=make_float4(0,0,0,0); }
  #pragma unroll
  for (int c=0;c<3;++c){
    const float tc = t[c];
    #pragma unroll
    for (int o=0;o<16;++o){
      float4 ws  = W[c*16+o],     ws2 = W[(c+3)*16+o];
      float4 wq  = W[(c+6)*16+o], wq2 = W[(c+9)*16+o];
      u[o] = f4fma(tc, make_float4(ws.x+ws2.x, ws.y+ws2.y, ws.z+ws2.z, ws.w+ws2.w), u[o]);
      q[o] = f4fma(tc, make_float4(wq.x+wq2.x, wq.y+wq2.y, wq.z+wq2.z, wq.w+wq2.w), q[o]);
    }
  }
  float4* up = (float4*)(U + (size_t)p*64);
  float4* dp = (float4*)(D + (size_t)p*64);
  #pragma unroll
  for (int o=0;o<16;++o){
    up[o] = u[o];
    dp[o] = make_float4(q[o].x-u[o].x, q[o].y-u[o].y, q[o].z-u[o].z, q[o].w-u[o].w);
  }
}

// ---------- two-layer edge conv: max_k prelu( prelu(U[nb]+D[p]) @ Wb ) ----------
// thread = (p, quarter of 16 out channels)
__global__ __launch_bounds__(256) void edge2_kernel(const float* __restrict__ U,
                                                    const float* __restrict__ Dp,
                                                    const int* __restrict__ idx,
                                                    const float* __restrict__ Wb,
                                                    const float* __restrict__ PA, int paa, int pab,
                                                    float* __restrict__ out, int coff){
  __shared__ __align__(16) float sW[64][68];
  const int tid = threadIdx.x;
  for (int i = tid; i < 1024; i += 256) {
    float4 w = *(const float4*)(Wb + (size_t)i*4);
    *(float4*)&sW[i>>4][(i&15)*4] = w;
  }
  const int t = blockIdx.x*256 + tid;
  const int q4 = t & 3, p = t >> 2, b = p >> 13;
  const float aa = PA[paa], ab = PA[pab];
  float dv[64];
  {
    const float4* dr = (const float4*)(Dp + (size_t)p*64);
    #pragma unroll
    for (int i=0;i<16;++i){
      float4 v = dr[i];
      dv[i*4]=v.x; dv[i*4+1]=v.y; dv[i*4+2]=v.z; dv[i*4+3]=v.w;
    }
  }
  __syncthreads();
  float4 mx[4];
  #pragma unroll
  for (int o=0;o<4;++o) mx[o] = make_float4(-INFINITY,-INFINITY,-INFINITY,-INFINITY);
  for (int k=0;k<10;++k) {
    int nb = idx[p*10+k];
    const float4* ur = (const float4*)(U + ((size_t)(b<<13)+nb)*64);
    float4 z[4];
    #pragma unroll
    for (int o=0;o<4;++o) z[o] = make_float4(0,0,0,0);
    #pragma unroll
    for (int c4=0;c4<16;++c4) {
      float4 uv = ur[c4];
      float h0 = preluf(uv.x + dv[c4*4+0], aa);
      float h1 = preluf(uv.y + dv[c4*4+1], aa);
      float h2 = preluf(uv.z + dv[c4*4+2], aa);
      float h3 = preluf(uv.w + dv[c4*4+3], aa);
      #pragma unroll
      for (int o=0;o<4;++o) {
        z[o] = f4fma(h0, *(const float4*)&sW[c4*4+0][q4*16+o*4], z[o]);
        z[o] = f4fma(h1, *(const float4*)&sW[c4*4+1][q4*16+o*4], z[o]);
        z[o] = f4fma(h2, *(const float4*)&sW[c4*4+2][q4*16+o*4], z[o]);
        z[o] = f4fma(h3, *(const float4*)&sW[c4*4+3][q4*16+o*4], z[o]);
      }
    }
    #pragma unroll
    for (int o=0;o<4;++o) {
      mx[o].x = fmaxf(mx[o].x, preluf(z[o].x, ab));
      mx[o].y = fmaxf(mx[o].y, preluf(z[o].y, ab));
      mx[o].z = fmaxf(mx[o].z, preluf(z[o].z, ab));
      mx[o].w = fmaxf(mx[o].w, preluf(z[o].w, ab));
    }
  }
  float4* op = (float4*)(out + (size_t)p*192 + coff + q4*16);
  #pragma unroll
  for (int o=0;o<4;++o) op[o] = mx[o];
}

// ---------- single-layer edge conv (conv3): max_k prelu(U[nb]+D[p]) ----------
__global__ __launch_bounds__(256) void edge1max_kernel(const float* __restrict__ U,
                                                       const float* __restrict__ Dp,
                                                       const int* __restrict__ idx,
                                                       const float* __restrict__ PA, int paa,
                                                       float* __restrict__ out, int coff){
  const int t = blockIdx.x*256 + threadIdx.x;
  const int hf = t & 1, p = t >> 1, b = p >> 13;
  const float aa = PA[paa];
  float dv[32];
  {
    const float4* dr = (const float4*)(Dp + (size_t)p*64 + hf*32);
    #pragma unroll
    for (int i=0;i<8;++i){
      float4 v = dr[i];
      dv[i*4]=v.x; dv[i*4+1]=v.y; dv[i*4+2]=v.z; dv[i*4+3]=v.w;
    }
  }
  float mx[32];
  #pragma unroll
  for (int o=0;o<32;++o) mx[o] = -INFINITY;
  for (int k=0;k<10;++k) {
    int nb = idx[p*10+k];
    const float4* ur = (const float4*)(U + ((size_t)(b<<13)+nb)*64 + hf*32);
    #pragma unroll
    for (int i=0;i<8;++i) {
      float4 v = ur[i];
      mx[i*4+0] = fmaxf(mx[i*4+0], preluf(v.x + dv[i*4+0], aa));
      mx[i*4+1] = fmaxf(mx[i*4+1], preluf(v.y + dv[i*4+1], aa));
      mx[i*4+2] = fmaxf(mx[i*4+2], preluf(v.z + dv[i*4+2], aa));
      mx[i*4+3] = fmaxf(mx[i*4+3], preluf(v.w + dv[i*4+3], aa));
    }
  }
  float4* op = (float4*)(out + (size_t)p*192 + coff + hf*32);
  #pragma unroll
  for (int i=0;i<8;++i) op[i] = make_float4(mx[i*4],mx[i*4+1],mx[i*4+2],mx[i*4+3]);
}

// ---------- tiled fp32 GEMM: C = prelu(A@B [+bias]) ; EPI2: column-max partials ----------
template<int EPI>   // 0: prelu->store, 1: +bias prelu->store, 2: prelu->colmax partial
__global__ __launch_bounds__(256) void gemm_kernel(const float* __restrict__ A, int lda,
                                                   const float* __restrict__ Bm, int ldb,
                                                   float* __restrict__ C, int ldc,
                                                   const float* __restrict__ bias,
                                                   const float* __restrict__ PA, int pidx,
                                                   int K, int Ntot){
  __shared__ __align__(16) float As[16][132];
  __shared__ __align__(16) float Bs[16][132];
  const int tid = threadIdx.x;
  const int m0 = blockIdx.x*128, n0 = blockIdx.y*128;
  const int tm = tid & 15, tn = tid >> 4;
  float acc[8][8];
  #pragma unroll
  for (int i=0;i<8;++i)
    #pragma unroll
    for (int j=0;j<8;++j) acc[i][j]=0.f;

  for (int k0=0;k0<K;k0+=16) {
    {
      int r = tid >> 2, kq = (tid&3)*4;
      #pragma unroll
      for (int it=0; it<2; ++it) {
        int rr = r + it*64;
        float4 v = *(const float4*)(A + (size_t)(m0+rr)*lda + k0 + kq);
        As[kq+0][rr]=v.x; As[kq+1][rr]=v.y; As[kq+2][rr]=v.z; As[kq+3][rr]=v.w;
      }
    }
    {
      int kk = tid >> 4, c = (tid&15)*8;
      const float* bp = Bm + (size_t)(k0+kk)*ldb + n0 + c;
      *(float4*)&Bs[kk][c]   = *(const float4*)bp;
      *(float4*)&Bs[kk][c+4] = *(const float4*)(bp+4);
    }
    __syncthreads();
    #pragma unroll
    for (int kk=0;kk<16;++kk) {
      float av[8], bv[8];
      *(float4*)&av[0] = *(const float4*)&As[kk][tm*8+0];
      *(float4*)&av[4] = *(const float4*)&As[kk][tm*8+4];
      *(float4*)&bv[0] = *(const float4*)&Bs[kk][tn*8+0];
      *(float4*)&bv[4] = *(const float4*)&Bs[kk][tn*8+4];
      #pragma unroll
      for (int i=0;i<8;++i)
        #pragma unroll
        for (int j=0;j<8;++j)
          acc[i][j] = fmaf(av[i], bv[j], acc[i][j]);
    }
    __syncthreads();
  }
  const float a = PA[pidx];
  if (EPI == 2) {
    #pragma unroll
    for (int j=0;j<8;++j) {
      float m = -INFINITY;
      #pragma unroll
      for (int i=0;i<8;++i) { float v = acc[i][j]; v = v>=0.f? v : a*v; m = fmaxf(m,v); }
      #pragma unroll
      for (int off=1;off<16;off<<=1) m = fmaxf(m, __shfl_xor(m, off));
      if (tm == 0) C[(size_t)blockIdx.x*Ntot + n0 + tn*8 + j] = m;
    }
  } else {
    float bcol[8];
    if (EPI==1) {
      int bb = m0 >> 13;
      #pragma unroll
      for (int j=0;j<8;++j) bcol[j] = bias[bb*256 + n0 + tn*8 + j];
    }
    #pragma unroll
    for (int i=0;i<8;++i) {
      float out[8];
      #pragma unroll
      for (int j=0;j<8;++j) {
        float v = acc[i][j] + (EPI==1 ? bcol[j] : 0.f);
        out[j] = v>=0.f? v : a*v;
      }
      float* cp = C + (size_t)(m0 + tm*8 + i)*ldc + n0 + tn*8;
      *(float4*)cp     = make_float4(out[0],out[1],out[2],out[3]);
      *(float4*)(cp+4) = make_float4(out[4],out[5],out[6],out[7]);
    }
  }
}

__global__ __launch_bounds__(256) void reduce_pmax(const float* __restrict__ pmax,
                                                   float* __restrict__ x5m){
  int t = blockIdx.x*256 + threadIdx.x;
  if (t < 4096) {
    int b = t >> 10, o = t & 1023;
    float m = -INFINITY;
    for (int mt=0; mt<64; ++mt) m = fmaxf(m, pmax[((size_t)(b*64+mt))*1024 + o]);
    x5m[t] = m;
  }
}

__global__ __launch_bounds__(256) void bias7_kernel(const float* __restrict__ x5m,
                                                    const float* __restrict__ W7,
                                                    float* __restrict__ b7){
  int b = blockIdx.x; int o = threadIdx.x;
  float s = 0.f;
  for (int j=0;j<1024;++j) s = fmaf(x5m[b*1024+j], W7[(size_t)(192+j)*256 + o], s);
  b7[b*256+o] = s;
}

__global__ __launch_bounds__(256) void final10_kernel(const float* __restrict__ y3,
                                                      const float* __restrict__ W10,
                                                      const float* __restrict__ PA,
                                                      float* __restrict__ out){
  int p = blockIdx.x*256 + threadIdx.x;
  const float4* r = (const float4*)(y3 + (size_t)p*128);
  float s0=0.f, s1=0.f;
  #pragma unroll
  for (int c4=0;c4<32;++c4){
    float4 v = r[c4];
    s0 = fmaf(v.x, W10[(c4*4+0)*2+0], s0); s1 = fmaf(v.x, W10[(c4*4+0)*2+1], s1);
    s0 = fmaf(v.y, W10[(c4*4+1)*2+0], s0); s1 = fmaf(v.y, W10[(c4*4+1)*2+1], s1);
    s0 = fmaf(v.z, W10[(c4*4+2)*2+0], s0); s1 = fmaf(v.z, W10[(c4*4+2)*2+1], s1);
    s0 = fmaf(v.w, W10[(c4*4+3)*2+0], s0); s1 = fmaf(v.w, W10[(c4*4+3)*2+1], s1);
  }
  float a = PA[9];
  out[p*2+0] = s0>=0.f? s0 : a*s0;
  out[p*2+1] = s1>=0.f? s1 : a*s1;
}

extern "C" void kernel_launch(void* const* d_in, const int* in_sizes, int n_in,
                              void* d_out, int out_size, void* d_ws, size_t ws_size,
                              hipStream_t stream) {
  const float* T   = (const float*)d_in[0];
  const float* W1  = (const float*)d_in[1];
  const float* W2  = (const float*)d_in[2];
  const float* W3  = (const float*)d_in[3];
  const float* W4  = (const float*)d_in[4];
  const float* W5  = (const float*)d_in[5];
  const float* W6  = (const float*)d_in[6];
  const float* W7  = (const float*)d_in[7];
  const float* W8  = (const float*)d_in[8];
  const float* W9  = (const float*)d_in[9];
  const float* W10 = (const float*)d_in[10];
  const float* PA  = (const float*)d_in[11];

  float* ws   = (float*)d_ws;
  float* x0   = ws + 0;                // 131072
  float* sqn0 = ws + 131072;           // 32768
  float* sqn1 = ws + 163840;           // 32768
  float* sqn2 = ws + 196608;           // 32768
  int*   idx0 = (int*)(ws + 229376);   // 327680
  int*   idx1 = (int*)(ws + 557056);   // 327680
  int*   idx2 = (int*)(ws + 884736);   // 327680
  float* xcat = ws + 1212416;          // 6291456  [B,N,192]
  float* pmax = ws + 7503872;          // 262144
  float* x5m  = ws + 7766016;          // 4096
  float* b7   = ws + 7770112;          // 1024
  float* y1   = ws + 7771136;          // 8388608  (aliased: U during convs)
  float* y2   = ws + 16159744;         // 8388608  (aliased: D during convs)
  float* y3   = xcat;                  // xcat dead after mlp7
  float* U    = y1;                    // [32768,64]
  float* D    = y2;                    // [32768,64]

  // conv1
  prep0_kernel<<<128, 256, 0, stream>>>(T, x0, sqn0);
  knn_kernel<4><<<dim3(64,4), 512, 0, stream>>>(x0, 4, 0, sqn0, idx0);
  prepUD12_kernel<<<128, 256, 0, stream>>>(T, W1, U, D);
  edge2_kernel<<<512, 256, 0, stream>>>(U, D, idx0, W2, PA, 0, 1, xcat, 0);

  // conv2
  sqnorm_kernel<<<128, 256, 0, stream>>>(xcat, 0, sqn1);
  knn_kernel<64><<<dim3(64,4), 512, 0, stream>>>(xcat, 192, 0, sqn1, idx1);
  prepUD64_kernel<<<128, 256, 0, stream>>>(xcat, 0, W3, U, D);
  edge2_kernel<<<512, 256, 0, stream>>>(U, D, idx1, W4, PA, 2, 3, xcat, 64);

  // conv3
  sqnorm_kernel<<<128, 256, 0, stream>>>(xcat, 64, sqn2);
  knn_kernel<64><<<dim3(64,4), 512, 0, stream>>>(xcat, 192, 64, sqn2, idx2);
  prepUD64_kernel<<<128, 256, 0, stream>>>(xcat, 64, W5, U, D);
  edge1max_kernel<<<256, 256, 0, stream>>>(U, D, idx2, PA, 4, xcat, 128);

  // head
  gemm_kernel<2><<<dim3(256,8), 256, 0, stream>>>(xcat, 192, W6, 1024, pmax, 0, nullptr, PA, 5, 192, 1024);
  reduce_pmax<<<16, 256, 0, stream>>>(pmax, x5m);
  bias7_kernel<<<4, 256, 0, stream>>>(x5m, W7, b7);
  gemm_kernel<1><<<dim3(256,2), 256, 0, stream>>>(xcat, 192, W7, 256, y1, 256, b7, PA, 6, 192, 256);
  gemm_kernel<0><<<dim3(256,2), 256, 0, stream>>>(y1, 256, W8, 256, y2, 256, nullptr, PA, 7, 256, 256);
  gemm_kernel<0><<<dim3(256,1), 256, 0, stream>>>(y2, 256, W9, 128, y3, 128, nullptr, PA, 8, 256, 128);
  final10_kernel<<<128, 256, 0, stream>>>(y3, W10, PA, (float*)d_out);
}

// Round 3
// 6110.076 us; speedup vs baseline: 1.2983x; 1.2983x over previous
//
#include <hip/hip_runtime.h>
#include <math.h>

#define NPTS 8192
#define KNNK 10

__device__ __forceinline__ float preluf(float v, float a){ return v >= 0.f ? v : a*v; }
__device__ __forceinline__ float4 f4fma(float a, float4 b, float4 c){
  return make_float4(fmaf(a,b.x,c.x), fmaf(a,b.y,c.y), fmaf(a,b.z,c.z), fmaf(a,b.w,c.w));
}
__device__ __forceinline__ bool lexless(float d1, int i1, float d2, int i2){
  return (d1 < d2) || (d1 == d2 && i1 < i2);
}

// ---------- prep: x0pad (targets padded to 4ch) + sqnorm ----------
__global__ __launch_bounds__(256) void prep0_kernel(const float* __restrict__ T,
                                                    float* __restrict__ x0,
                                                    float* __restrict__ sqn){
  int p = blockIdx.x*256 + threadIdx.x;
  float t0 = T[p*3+0], t1 = T[p*3+1], t2 = T[p*3+2];
  *(float4*)(x0 + (size_t)p*4) = make_float4(t0,t1,t2,0.f);
  float s = fmaf(t0,t0,0.f); s = fmaf(t1,t1,s); s = fmaf(t2,t2,s); s = fmaf(0.f,0.f,s);
  sqn[p] = s;
}

__global__ __launch_bounds__(256) void sqnorm_kernel(const float* __restrict__ XC, int cin,
                                                     float* __restrict__ sqn){
  int p = blockIdx.x*256 + threadIdx.x;
  const float4* r = (const float4*)(XC + (size_t)p*192 + cin);
  float s = 0.f;
  #pragma unroll
  for (int c4=0;c4<16;++c4){
    float4 v = r[c4];
    s = fmaf(v.x,v.x,s); s = fmaf(v.y,v.y,s); s = fmaf(v.z,v.z,s); s = fmaf(v.w,v.w,s);
  }
  sqn[p] = s;
}

// ---------- fused distance-GEMM + partial top-10 KNN ----------
// 256 thr (4 waves), block tile 128q x 128j, thread tile 8x8, j-range split by
// blockIdx.z (2 halves -> 512 blocks -> 2 blocks/CU -> 2 waves/SIMD).
// tn=tid&15 (fast-varying) drives all LDS bank indices; B cols XOR-swizzled.
// dch in two 64-col chunks (stride 68) aliased over xjT; per-thread top-10
// over a 64-col stripe; in-block 2-way merge -> global partial lists.
template<int C>
__global__ __launch_bounds__(256, 2) void knn_kernel(const float* __restrict__ X, int ldx, int coff,
                                                     const float* __restrict__ sqn,
                                                     float* __restrict__ pd, int* __restrict__ pi){
  __shared__ __align__(16) float xqT[C*132];
  __shared__ __align__(16) float uni[128*84];   // xjT[C][132] | dch[128][68] | lists[128][84]
  __shared__ float s_x2q[128];
  __shared__ float s_x2j[128];

  const int b   = blockIdx.y;
  const int q0  = blockIdx.x * 128;
  const int jh  = blockIdx.z;
  const int tid = threadIdx.x;
  const int tn  = tid & 15;     // j-group (8 j)
  const int tm  = tid >> 4;     // q-group (8 q)
  const int tq  = tid & 127;    // scan: query
  const int th  = tid >> 7;     // scan: half (64 j-cols)

  const float* Xb = X + (size_t)b * NPTS * ldx + coff;

  // stage queries transposed: xqT[c][q], stride 132
  for (int i = tid; i < 128*(C/4); i += 256) {
    int q = i & 127, c4 = (i >> 7) << 2;
    float4 v = *(const float4*)(Xb + (size_t)(q0+q)*ldx + c4);
    xqT[(c4+0)*132+q] = v.x; xqT[(c4+1)*132+q] = v.y;
    xqT[(c4+2)*132+q] = v.z; xqT[(c4+3)*132+q] = v.w;
  }
  if (tid < 128) s_x2q[tid] = sqn[b*NPTS + q0 + tid];

  const int sw  = ((tn>>2)&3) << 2;
  const int bp0 = (tn*8)     ^ sw;
  const int bp1 = (tn*8 + 4) ^ sw;

  float bd[10]; int bi[10];
  #pragma unroll
  for (int u=0;u<10;++u){ bd[u] = INFINITY; bi[u] = 0x7fffffff; }

  for (int t = 0; t < 32; ++t) {
    const int j0 = jh*4096 + t*128;
    // stage xj transposed + swizzled: uni[c][pj], stride 132
    for (int i = tid; i < 128*(C/4); i += 256) {
      int j = i & 127, c4 = (i >> 7) << 2;
      float4 v = *(const float4*)(Xb + (size_t)(j0+j)*ldx + c4);
      int pj = j ^ (((j>>5)&3) << 2);
      uni[(c4+0)*132+pj] = v.x; uni[(c4+1)*132+pj] = v.y;
      uni[(c4+2)*132+pj] = v.z; uni[(c4+3)*132+pj] = v.w;
    }
    if (tid < 128) s_x2j[tid] = sqn[b*NPTS + j0 + tid];
    __syncthreads();  // staging done (covers xq staging at t=0)

    float acc[8][8];
    #pragma unroll
    for (int i=0;i<8;++i)
      #pragma unroll
      for (int j=0;j<8;++j) acc[i][j] = 0.f;

    #pragma unroll 8
    for (int kk=0; kk<C; ++kk) {
      float av[8], bv[8];
      *(float4*)&av[0] = *(const float4*)&xqT[kk*132 + tm*8];
      *(float4*)&av[4] = *(const float4*)&xqT[kk*132 + tm*8 + 4];
      *(float4*)&bv[0] = *(const float4*)&uni[kk*132 + bp0];
      *(float4*)&bv[4] = *(const float4*)&uni[kk*132 + bp1];
      #pragma unroll
      for (int i=0;i<8;++i)
        #pragma unroll
        for (int j=0;j<8;++j)
          acc[i][j] = fmaf(av[i], bv[j], acc[i][j]);
    }
    __syncthreads();  // gemm reads done; uni becomes dch[128][68]

    #pragma unroll
    for (int h=0; h<2; ++h) {
      // write distance chunk h: col = tn*4+jj  <->  j = tn*8 + h*4 + jj
      #pragma unroll
      for (int qi=0; qi<8; ++qi) {
        const int row = tm*8 + qi;
        const float xq2 = s_x2q[row];
        float4 v;
        v.x = xq2 + s_x2j[tn*8 + h*4 + 0] - 2.f*acc[qi][h*4+0];
        v.y = xq2 + s_x2j[tn*8 + h*4 + 1] - 2.f*acc[qi][h*4+1];
        v.z = xq2 + s_x2j[tn*8 + h*4 + 2] - 2.f*acc[qi][h*4+2];
        v.w = xq2 + s_x2j[tn*8 + h*4 + 3] - 2.f*acc[qi][h*4+3];
        *(float4*)&uni[row*68 + tn*4] = v;
      }
      __syncthreads();  // dch chunk written
      // scan chunk h: thread (tq, th) reads cols th*32..+31
      #pragma unroll
      for (int w4=0; w4<8; ++w4) {
        const int c4 = th*32 + w4*4;
        float4 dv = *(const float4*)&uni[tq*68 + c4];
        const int jb = j0 + (c4>>2)*8 + h*4;
        float dd[4] = {dv.x, dv.y, dv.z, dv.w};
        #pragma unroll
        for (int u=0;u<4;++u) {
          float d = dd[u]; int jj = jb + u;
          if (lexless(d, jj, bd[9], bi[9])) {
            bd[9] = d; bi[9] = jj;
            #pragma unroll
            for (int s=8;s>=0;--s) {
              if (lexless(bd[s+1], bi[s+1], bd[s], bi[s])) {
                float td = bd[s]; bd[s] = bd[s+1]; bd[s+1] = td;
                int ti = bi[s]; bi[s] = bi[s+1]; bi[s+1] = ti;
              }
            }
          }
        }
      }
      __syncthreads();  // scan done (protects next chunk write / next tile staging)
    }
  }

  // ---- in-block merge of the 2 per-thread lists per query ----
  #pragma unroll
  for (int u=0;u<10;++u) {
    uni[tq*84 + th*20 + u]      = bd[u];
    uni[tq*84 + th*20 + 10 + u] = __int_as_float(bi[u]);
  }
  __syncthreads();
  if (tid < 128) {
    const float* row = &uni[tid*84];
    int ia=0, ib2=0;
    size_t base = ((size_t)jh*(4*NPTS) + (size_t)b*NPTS + q0 + tid)*10;
    #pragma unroll
    for (int u=0;u<10;++u) {
      float da = row[ia], db = row[20+ib2];
      int ja = __float_as_int(row[10+ia]), jb = __float_as_int(row[30+ib2]);
      bool ta = lexless(da, ja, db, jb);
      pd[base+u] = ta ? da : db;
      pi[base+u] = ta ? ja : jb;
      ia += ta ? 1 : 0; ib2 += ta ? 0 : 1;
    }
  }
}

// ---------- merge the 2 j-half partial lists -> final idx ----------
__global__ __launch_bounds__(256) void knnmerge_kernel(const float* __restrict__ pd,
                                                       const int* __restrict__ pi,
                                                       int* __restrict__ idxout){
  int p = blockIdx.x*256 + threadIdx.x;   // 0..32767
  const float* da = pd + (size_t)p*10;
  const float* db = pd + (size_t)(4*NPTS)*10 + (size_t)p*10;
  const int*   ja = pi + (size_t)p*10;
  const int*   jb = pi + (size_t)(4*NPTS)*10 + (size_t)p*10;
  int ia=0, ib=0;
  int* op = idxout + (size_t)p*10;
  #pragma unroll
  for (int u=0;u<10;++u){
    float x = da[ia], y = db[ib];
    int jx = ja[ia], jy = jb[ib];
    bool t = lexless(x, jx, y, jy);
    op[u] = t ? jx : jy;
    ia += t ? 1 : 0; ib += t ? 0 : 1;
  }
}

// ---------- prep U/D for 64-ch edge conv: U = X@W[0:64], D = X@(W[64:128]-W[0:64]) ----------
__global__ __launch_bounds__(256) void prepUD64_kernel(const float* __restrict__ XC, int cin,
                                                       const float* __restrict__ W,
                                                       float* __restrict__ U,
                                                       float* __restrict__ D){
  int p = blockIdx.x*256 + threadIdx.x;
  float x[64];
  {
    const float4* xr = (const float4*)(XC + (size_t)p*192 + cin);
    #pragma unroll
    for (int c4=0;c4<16;++c4){
      float4 v = xr[c4];
      x[c4*4]=v.x; x[c4*4+1]=v.y; x[c4*4+2]=v.z; x[c4*4+3]=v.w;
    }
  }
  const float4* W4 = (const float4*)W;
  float4 z[16];
  #pragma unroll
  for (int o=0;o<16;++o) z[o] = make_float4(0,0,0,0);
  #pragma unroll
  for (int c=0;c<64;++c) {
    const float xc = x[c];
    #pragma unroll
    for (int o=0;o<16;++o) z[o] = f4fma(xc, W4[c*16+o], z[o]);
  }
  float4* up = (float4*)(U + (size_t)p*64);
  #pragma unroll
  for (int o=0;o<16;++o) up[o] = z[o];
  #pragma unroll
  for (int o=0;o<16;++o) z[o] = make_float4(0,0,0,0);
  #pragma unroll
  for (int c=0;c<64;++c) {
    const float xc = x[c];
    #pragma unroll
    for (int o=0;o<16;++o) {
      float4 wt = W4[c*16+o], wb = W4[(64+c)*16+o];
      float4 wd = make_float4(wb.x-wt.x, wb.y-wt.y, wb.z-wt.z, wb.w-wt.w);
      z[o] = f4fma(xc, wd, z[o]);
    }
  }
  float4* dp = (float4*)(D + (size_t)p*64);
  #pragma unroll
  for (int o=0;o<16;++o) dp[o] = z[o];
}

// ---------- prep U/D for conv1 (targets, 12-ch edge feats collapse to 3) ----------
__global__ __launch_bounds__(256) void prepUD12_kernel(const float* __restrict__ T,
                                                       const float* __restrict__ W1,
                                                       float* __restrict__ U,
                                                       float* __restrict__ D){
  int p = blockIdx.x*256 + threadIdx.x;
  float t[3] = {T[p*3+0], T[p*3+1], T[p*3+2]};
  const float4* W = (const float4*)W1;
  float4 u[16], q[16];
  #pragma unroll
  for (int o=0;o<16;++o){ u[o]=make_float4(0,0,0,0); q[o]=make_float4(0,0,0,0); }
  #pragma unroll
  for (int c=0;c<3;++c){
    const float tc = t[c];
    #pragma unroll
    for (int o=0;o<16;++o){
      float4 ws  = W[c*16+o],     ws2 = W[(c+3)*16+o];
      float4 wq  = W[(c+6)*16+o], wq2 = W[(c+9)*16+o];
      u[o] = f4fma(tc, make_float4(ws.x+ws2.x, ws.y+ws2.y, ws.z+ws2.z, ws.w+ws2.w), u[o]);
      q[o] = f4fma(tc, make_float4(wq.x+wq2.x, wq.y+wq2.y, wq.z+wq2.z, wq.w+wq2.w), q[o]);
    }
  }
  float4* up = (float4*)(U + (size_t)p*64);
  float4* dp = (float4*)(D + (size_t)p*64);
  #pragma unroll
  for (int o=0;o<16;++o){
    up[o] = u[o];
    dp[o] = make_float4(q[o].x-u[o].x, q[o].y-u[o].y, q[o].z-u[o].z, q[o].w-u[o].w);
  }
}

// ---------- two-layer edge conv: max_k prelu( prelu(U[nb]+D[p]) @ Wb ) ----------
__global__ __launch_bounds__(256) void edge2_kernel(const float* __restrict__ U,
                                                    const float* __restrict__ Dp,
                                                    const int* __restrict__ idx,
                                                    const float* __restrict__ Wb,
                                                    const float* __restrict__ PA, int paa, int pab,
                                                    float* __restrict__ out, int coff){
  __shared__ __align__(16) float sW[64][68];
  const int tid = threadIdx.x;
  for (int i = tid; i < 1024; i += 256) {
    float4 w = *(const float4*)(Wb + (size_t)i*4);
    *(float4*)&sW[i>>4][(i&15)*4] = w;
  }
  const int t = blockIdx.x*256 + tid;
  const int q4 = t & 3, p = t >> 2, b = p >> 13;
  const float aa = PA[paa], ab = PA[pab];
  float dv[64];
  {
    const float4* dr = (const float4*)(Dp + (size_t)p*64);
    #pragma unroll
    for (int i=0;i<16;++i){
      float4 v = dr[i];
      dv[i*4]=v.x; dv[i*4+1]=v.y; dv[i*4+2]=v.z; dv[i*4+3]=v.w;
    }
  }
  __syncthreads();
  float4 mx[4];
  #pragma unroll
  for (int o=0;o<4;++o) mx[o] = make_float4(-INFINITY,-INFINITY,-INFINITY,-INFINITY);
  for (int k=0;k<10;++k) {
    int nb = idx[p*10+k];
    const float4* ur = (const float4*)(U + ((size_t)(b<<13)+nb)*64);
    float4 z[4];
    #pragma unroll
    for (int o=0;o<4;++o) z[o] = make_float4(0,0,0,0);
    #pragma unroll
    for (int c4=0;c4<16;++c4) {
      float4 uv = ur[c4];
      float h0 = preluf(uv.x + dv[c4*4+0], aa);
      float h1 = preluf(uv.y + dv[c4*4+1], aa);
      float h2 = preluf(uv.z + dv[c4*4+2], aa);
      float h3 = preluf(uv.w + dv[c4*4+3], aa);
      #pragma unroll
      for (int o=0;o<4;++o) {
        z[o] = f4fma(h0, *(const float4*)&sW[c4*4+0][q4*16+o*4], z[o]);
        z[o] = f4fma(h1, *(const float4*)&sW[c4*4+1][q4*16+o*4], z[o]);
        z[o] = f4fma(h2, *(const float4*)&sW[c4*4+2][q4*16+o*4], z[o]);
        z[o] = f4fma(h3, *(const float4*)&sW[c4*4+3][q4*16+o*4], z[o]);
      }
    }
    #pragma unroll
    for (int o=0;o<4;++o) {
      mx[o].x = fmaxf(mx[o].x, preluf(z[o].x, ab));
      mx[o].y = fmaxf(mx[o].y, preluf(z[o].y, ab));
      mx[o].z = fmaxf(mx[o].z, preluf(z[o].z, ab));
      mx[o].w = fmaxf(mx[o].w, preluf(z[o].w, ab));
    }
  }
  float4* op = (float4*)(out + (size_t)p*192 + coff + q4*16);
  #pragma unroll
  for (int o=0;o<4;++o) op[o] = mx[o];
}

// ---------- single-layer edge conv (conv3): max_k prelu(U[nb]+D[p]) ----------
__global__ __launch_bounds__(256) void edge1max_kernel(const float* __restrict__ U,
                                                       const float* __restrict__ Dp,
                                                       const int* __restrict__ idx,
                                                       const float* __restrict__ PA, int paa,
                                                       float* __restrict__ out, int coff){
  const int t = blockIdx.x*256 + threadIdx.x;
  const int hf = t & 1, p = t >> 1, b = p >> 13;
  const float aa = PA[paa];
  float dv[32];
  {
    const float4* dr = (const float4*)(Dp + (size_t)p*64 + hf*32);
    #pragma unroll
    for (int i=0;i<8;++i){
      float4 v = dr[i];
      dv[i*4]=v.x; dv[i*4+1]=v.y; dv[i*4+2]=v.z; dv[i*4+3]=v.w;
    }
  }
  float mx[32];
  #pragma unroll
  for (int o=0;o<32;++o) mx[o] = -INFINITY;
  for (int k=0;k<10;++k) {
    int nb = idx[p*10+k];
    const float4* ur = (const float4*)(U + ((size_t)(b<<13)+nb)*64 + hf*32);
    #pragma unroll
    for (int i=0;i<8;++i) {
      float4 v = ur[i];
      mx[i*4+0] = fmaxf(mx[i*4+0], preluf(v.x + dv[i*4+0], aa));
      mx[i*4+1] = fmaxf(mx[i*4+1], preluf(v.y + dv[i*4+1], aa));
      mx[i*4+2] = fmaxf(mx[i*4+2], preluf(v.z + dv[i*4+2], aa));
      mx[i*4+3] = fmaxf(mx[i*4+3], preluf(v.w + dv[i*4+3], aa));
    }
  }
  float4* op = (float4*)(out + (size_t)p*192 + coff + hf*32);
  #pragma unroll
  for (int i=0;i<8;++i) op[i] = make_float4(mx[i*4],mx[i*4+1],mx[i*4+2],mx[i*4+3]);
}

// ---------- tiled fp32 GEMM: C = prelu(A@B [+bias]) ; EPI2: column-max partials ----------
template<int EPI>   // 0: prelu->store, 1: +bias prelu->store, 2: prelu->colmax partial
__global__ __launch_bounds__(256) void gemm_kernel(const float* __restrict__ A, int lda,
                                                   const float* __restrict__ Bm, int ldb,
                                                   float* __restrict__ C, int ldc,
                                                   const float* __restrict__ bias,
                                                   const float* __restrict__ PA, int pidx,
                                                   int K, int Ntot){
  __shared__ __align__(16) float As[16][132];
  __shared__ __align__(16) float Bs[16][132];
  const int tid = threadIdx.x;
  const int m0 = blockIdx.x*128, n0 = blockIdx.y*128;
  const int tm = tid & 15, tn = tid >> 4;
  float acc[8][8];
  #pragma unroll
  for (int i=0;i<8;++i)
    #pragma unroll
    for (int j=0;j<8;++j) acc[i][j]=0.f;

  for (int k0=0;k0<K;k0+=16) {
    {
      int r = tid >> 2, kq = (tid&3)*4;
      #pragma unroll
      for (int it=0; it<2; ++it) {
        int rr = r + it*64;
        float4 v = *(const float4*)(A + (size_t)(m0+rr)*lda + k0 + kq);
        As[kq+0][rr]=v.x; As[kq+1][rr]=v.y; As[kq+2][rr]=v.z; As[kq+3][rr]=v.w;
      }
    }
    {
      int kk = tid >> 4, c = (tid&15)*8;
      const float* bp = Bm + (size_t)(k0+kk)*ldb + n0 + c;
      *(float4*)&Bs[kk][c]   = *(const float4*)bp;
      *(float4*)&Bs[kk][c+4] = *(const float4*)(bp+4);
    }
    __syncthreads();
    #pragma unroll
    for (int kk=0;kk<16;++kk) {
      float av[8], bv[8];
      *(float4*)&av[0] = *(const float4*)&As[kk][tm*8+0];
      *(float4*)&av[4] = *(const float4*)&As[kk][tm*8+4];
      *(float4*)&bv[0] = *(const float4*)&Bs[kk][tn*8+0];
      *(float4*)&bv[4] = *(const float4*)&Bs[kk][tn*8+4];
      #pragma unroll
      for (int i=0;i<8;++i)
        #pragma unroll
        for (int j=0;j<8;++j)
          acc[i][j] = fmaf(av[i], bv[j], acc[i][j]);
    }
    __syncthreads();
  }
  const float a = PA[pidx];
  if (EPI == 2) {
    #pragma unroll
    for (int j=0;j<8;++j) {
      float m = -INFINITY;
      #pragma unroll
      for (int i=0;i<8;++i) { float v = acc[i][j]; v = v>=0.f? v : a*v; m = fmaxf(m,v); }
      #pragma unroll
      for (int off=1;off<16;off<<=1) m = fmaxf(m, __shfl_xor(m, off));
      if (tm == 0) C[(size_t)blockIdx.x*Ntot + n0 + tn*8 + j] = m;
    }
  } else {
    float bcol[8];
    if (EPI==1) {
      int bb = m0 >> 13;
      #pragma unroll
      for (int j=0;j<8;++j) bcol[j] = bias[bb*256 + n0 + tn*8 + j];
    }
    #pragma unroll
    for (int i=0;i<8;++i) {
      float out[8];
      #pragma unroll
      for (int j=0;j<8;++j) {
        float v = acc[i][j] + (EPI==1 ? bcol[j] : 0.f);
        out[j] = v>=0.f? v : a*v;
      }
      float* cp = C + (size_t)(m0 + tm*8 + i)*ldc + n0 + tn*8;
      *(float4*)cp     = make_float4(out[0],out[1],out[2],out[3]);
      *(float4*)(cp+4) = make_float4(out[4],out[5],out[6],out[7]);
    }
  }
}

__global__ __launch_bounds__(256) void reduce_pmax(const float* __restrict__ pmax,
                                                   float* __restrict__ x5m){
  int t = blockIdx.x*256 + threadIdx.x;
  if (t < 4096) {
    int b = t >> 10, o = t & 1023;
    float m = -INFINITY;
    for (int mt=0; mt<64; ++mt) m = fmaxf(m, pmax[((size_t)(b*64+mt))*1024 + o]);
    x5m[t] = m;
  }
}

__global__ __launch_bounds__(256) void bias7_kernel(const float* __restrict__ x5m,
                                                    const float* __restrict__ W7,
                                                    float* __restrict__ b7){
  int b = blockIdx.x; int o = threadIdx.x;
  float s = 0.f;
  for (int j=0;j<1024;++j) s = fmaf(x5m[b*1024+j], W7[(size_t)(192+j)*256 + o], s);
  b7[b*256+o] = s;
}

__global__ __launch_bounds__(256) void final10_kernel(const float* __restrict__ y3,
                                                      const float* __restrict__ W10,
                                                      const float* __restrict__ PA,
                                                      float* __restrict__ out){
  int p = blockIdx.x*256 + threadIdx.x;
  const float4* r = (const float4*)(y3 + (size_t)p*128);
  float s0=0.f, s1=0.f;
  #pragma unroll
  for (int c4=0;c4<32;++c4){
    float4 v = r[c4];
    s0 = fmaf(v.x, W10[(c4*4+0)*2+0], s0); s1 = fmaf(v.x, W10[(c4*4+0)*2+1], s1);
    s0 = fmaf(v.y, W10[(c4*4+1)*2+0], s0); s1 = fmaf(v.y, W10[(c4*4+1)*2+1], s1);
    s0 = fmaf(v.z, W10[(c4*4+2)*2+0], s0); s1 = fmaf(v.z, W10[(c4*4+2)*2+1], s1);
    s0 = fmaf(v.w, W10[(c4*4+3)*2+0], s0); s1 = fmaf(v.w, W10[(c4*4+3)*2+1], s1);
  }
  float a = PA[9];
  out[p*2+0] = s0>=0.f? s0 : a*s0;
  out[p*2+1] = s1>=0.f? s1 : a*s1;
}

extern "C" void kernel_launch(void* const* d_in, const int* in_sizes, int n_in,
                              void* d_out, int out_size, void* d_ws, size_t ws_size,
                              hipStream_t stream) {
  const float* T   = (const float*)d_in[0];
  const float* W1  = (const float*)d_in[1];
  const float* W2  = (const float*)d_in[2];
  const float* W3  = (const float*)d_in[3];
  const float* W4  = (const float*)d_in[4];
  const float* W5  = (const float*)d_in[5];
  const float* W6  = (const float*)d_in[6];
  const float* W7  = (const float*)d_in[7];
  const float* W8  = (const float*)d_in[8];
  const float* W9  = (const float*)d_in[9];
  const float* W10 = (const float*)d_in[10];
  const float* PA  = (const float*)d_in[11];

  float* ws   = (float*)d_ws;
  float* x0   = ws + 0;                // 131072
  float* sqn0 = ws + 131072;           // 32768
  float* sqn1 = ws + 163840;           // 32768
  float* sqn2 = ws + 196608;           // 32768
  int*   idx0 = (int*)(ws + 229376);   // 327680
  int*   idx1 = (int*)(ws + 557056);   // 327680
  int*   idx2 = (int*)(ws + 884736);   // 327680
  float* xcat = ws + 1212416;          // 6291456  [B,N,192]
  float* pmax = ws + 7503872;          // 262144
  float* x5m  = ws + 7766016;          // 4096
  float* b7   = ws + 7770112;          // 1024
  float* y1   = ws + 7771136;          // 8388608  (aliased: U + knn partials)
  float* y2   = ws + 16159744;         // 8388608  (aliased: D)
  float* y3   = xcat;                  // xcat dead after mlp7
  float* U    = y1;                    // [32768,64]
  float* D    = y2;                    // [32768,64]
  float* pd   = y1;                    // knn partial dists  [2][32768][10]
  int*   pi   = (int*)(y1 + 655360);   // knn partial idx    [2][32768][10]

  // conv1
  prep0_kernel<<<128, 256, 0, stream>>>(T, x0, sqn0);
  knn_kernel<4><<<dim3(64,4,2), 256, 0, stream>>>(x0, 4, 0, sqn0, pd, pi);
  knnmerge_kernel<<<128, 256, 0, stream>>>(pd, pi, idx0);
  prepUD12_kernel<<<128, 256, 0, stream>>>(T, W1, U, D);
  edge2_kernel<<<512, 256, 0, stream>>>(U, D, idx0, W2, PA, 0, 1, xcat, 0);

  // conv2
  sqnorm_kernel<<<128, 256, 0, stream>>>(xcat, 0, sqn1);
  knn_kernel<64><<<dim3(64,4,2), 256, 0, stream>>>(xcat, 192, 0, sqn1, pd, pi);
  knnmerge_kernel<<<128, 256, 0, stream>>>(pd, pi, idx1);
  prepUD64_kernel<<<128, 256, 0, stream>>>(xcat, 0, W3, U, D);
  edge2_kernel<<<512, 256, 0, stream>>>(U, D, idx1, W4, PA, 2, 3, xcat, 64);

  // conv3
  sqnorm_kernel<<<128, 256, 0, stream>>>(xcat, 64, sqn2);
  knn_kernel<64><<<dim3(64,4,2), 256, 0, stream>>>(xcat, 192, 64, sqn2, pd, pi);
  knnmerge_kernel<<<128, 256, 0, stream>>>(pd, pi, idx2);
  prepUD64_kernel<<<128, 256, 0, stream>>>(xcat, 64, W5, U, D);
  edge1max_kernel<<<256, 256, 0, stream>>>(U, D, idx2, PA, 4, xcat, 128);

  // head
  gemm_kernel<2><<<dim3(256,8), 256, 0, stream>>>(xcat, 192, W6, 1024, pmax, 0, nullptr, PA, 5, 192, 1024);
  reduce_pmax<<<16, 256, 0, stream>>>(pmax, x5m);
  bias7_kernel<<<4, 256, 0, stream>>>(x5m, W7, b7);
  gemm_kernel<1><<<dim3(256,2), 256, 0, stream>>>(xcat, 192, W7, 256, y1, 256, b7, PA, 6, 192, 256);
  gemm_kernel<0><<<dim3(256,2), 256, 0, stream>>>(y1, 256, W8, 256, y2, 256, nullptr, PA, 7, 256, 256);
  gemm_kernel<0><<<dim3(256,1), 256, 0, stream>>>(y2, 256, W9, 128, y3, 128, nullptr, PA, 8, 256, 128);
  final10_kernel<<<128, 256, 0, stream>>>(y3, W10, PA, (float*)d_out);
}

// Round 4
// 4040.933 us; speedup vs baseline: 1.9631x; 1.5120x over previous
//
#include <hip/hip_runtime.h>
#include <math.h>

#define NPTS 8192
#define KNNK 10

typedef __attribute__((ext_vector_type(8))) short bf16x8s;
typedef __attribute__((ext_vector_type(4))) float f32x4;

__device__ __forceinline__ float preluf(float v, float a){ return v >= 0.f ? v : a*v; }
__device__ __forceinline__ float4 f4fma(float a, float4 b, float4 c){
  return make_float4(fmaf(a,b.x,c.x), fmaf(a,b.y,c.y), fmaf(a,b.z,c.z), fmaf(a,b.w,c.w));
}

// ---- u64 lex key: (ordered-float-bits(d) << 32) | j ; smaller key = better ----
__device__ __forceinline__ unsigned long long dkey(float d, int j){
  int s = __float_as_int(d);
  unsigned u = (unsigned)s ^ (unsigned)((s>>31) | 0x80000000);
  return ((unsigned long long)u << 32) | (unsigned)j;
}
// branchless insert into ascending sorted-10
__device__ __forceinline__ void ins10(unsigned long long* bk, unsigned long long t){
  #pragma unroll
  for (int s=0;s<10;++s){
    bool c = t < bk[s];
    unsigned long long mn = c ? t : bk[s];
    unsigned long long mx = c ? bk[s] : t;
    bk[s] = mn; t = mx;
  }
}
// split float into bf16 hi/lo (rne); returns packed hi pair, sets lo pair
__device__ __forceinline__ unsigned bfsplit2(float a, float b, unsigned& lo2){
  unsigned ua = __float_as_uint(a), ub = __float_as_uint(b);
  unsigned ha = (ua + 0x7FFFu + ((ua>>16)&1u)) & 0xFFFF0000u;
  unsigned hb = (ub + 0x7FFFu + ((ub>>16)&1u)) & 0xFFFF0000u;
  float ra = a - __uint_as_float(ha);
  float rb = b - __uint_as_float(hb);
  unsigned la = __float_as_uint(ra), lb = __float_as_uint(rb);
  unsigned qa = (la + 0x7FFFu + ((la>>16)&1u)) >> 16;
  unsigned qb = (lb + 0x7FFFu + ((lb>>16)&1u)) & 0xFFFF0000u;
  lo2 = qa | qb;
  return (ha >> 16) | hb;
}

// ---------- prep: x0pad (targets padded to 4ch) + sqnorm ----------
__global__ __launch_bounds__(256) void prep0_kernel(const float* __restrict__ T,
                                                    float* __restrict__ x0,
                                                    float* __restrict__ sqn){
  int p = blockIdx.x*256 + threadIdx.x;
  float t0 = T[p*3+0], t1 = T[p*3+1], t2 = T[p*3+2];
  *(float4*)(x0 + (size_t)p*4) = make_float4(t0,t1,t2,0.f);
  float s = fmaf(t0,t0,0.f); s = fmaf(t1,t1,s); s = fmaf(t2,t2,s); s = fmaf(0.f,0.f,s);
  sqn[p] = s;
}

__global__ __launch_bounds__(256) void sqnorm_kernel(const float* __restrict__ XC, int cin,
                                                     float* __restrict__ sqn){
  int p = blockIdx.x*256 + threadIdx.x;
  const float4* r = (const float4*)(XC + (size_t)p*192 + cin);
  float s = 0.f;
  #pragma unroll
  for (int c4=0;c4<16;++c4){
    float4 v = r[c4];
    s = fmaf(v.x,v.x,s); s = fmaf(v.y,v.y,s); s = fmaf(v.z,v.z,s); s = fmaf(v.w,v.w,s);
  }
  sqn[p] = s;
}

// ---------- KNN for C=64 features: MFMA bf16 hi/lo distance GEMM + u64 top-10 ----------
// 256 thr (4 waves), tile 128q x 128j, jh splits j-range in 2 -> 512 blocks (2/CU).
__global__ __launch_bounds__(256, 2) void knn64_kernel(const float* __restrict__ X, int ldx, int coff,
                                                       const float* __restrict__ sqn,
                                                       unsigned long long* __restrict__ pu){
  __shared__ __align__(16) unsigned short xq[2*128*72];  // [hilo][q][72] bf16 bits
  __shared__ __align__(16) unsigned char uni[36864];     // xj [2][128][72] | dch[128][68] f32 | lists
  __shared__ float s_x2q[128];
  __shared__ float s_x2j[128];

  unsigned short* xj = (unsigned short*)uni;
  float* dch = (float*)uni;
  unsigned long long* lst = (unsigned long long*)uni;

  const int b   = blockIdx.y;
  const int q0  = blockIdx.x * 128;
  const int jh  = blockIdx.z;
  const int tid = threadIdx.x;
  const int L   = tid & 63;
  const int w   = tid >> 6;
  const int lm  = L & 15;
  const int kg  = L >> 4;
  const int tq  = tid & 127;
  const int th  = tid >> 7;

  const float* Xb = X + (size_t)b * NPTS * ldx + coff;

  // stage queries (hi/lo bf16), once
  #pragma unroll
  for (int s=0;s<8;++s){
    int e = tid + s*256;                 // 128 pts x 16 c4-groups
    int r = e >> 4, c4 = (e & 15) << 2;
    float4 v = *(const float4*)(Xb + (size_t)(q0+r)*ldx + c4);
    unsigned lo01, lo23;
    unsigned hi01 = bfsplit2(v.x, v.y, lo01);
    unsigned hi23 = bfsplit2(v.z, v.w, lo23);
    uint2 hp; hp.x = hi01; hp.y = hi23;
    uint2 lp; lp.x = lo01; lp.y = lo23;
    *(uint2*)&xq[r*72 + c4]        = hp;
    *(uint2*)&xq[9216 + r*72 + c4] = lp;
  }
  if (tid < 128) s_x2q[tid] = sqn[b*NPTS + q0 + tid];

  unsigned long long bk[10];
  #pragma unroll
  for (int u=0;u<10;++u) bk[u] = ~0ULL;

  for (int t = 0; t < 32; ++t) {
    const int j0 = jh*4096 + t*128;
    // stage xj hi/lo
    #pragma unroll
    for (int s=0;s<8;++s){
      int e = tid + s*256;
      int r = e >> 4, c4 = (e & 15) << 2;
      float4 v = *(const float4*)(Xb + (size_t)(j0+r)*ldx + c4);
      unsigned lo01, lo23;
      unsigned hi01 = bfsplit2(v.x, v.y, lo01);
      unsigned hi23 = bfsplit2(v.z, v.w, lo23);
      uint2 hp; hp.x = hi01; hp.y = hi23;
      uint2 lp; lp.x = lo01; lp.y = lo23;
      *(uint2*)&xj[r*72 + c4]        = hp;
      *(uint2*)&xj[9216 + r*72 + c4] = lp;
    }
    if (tid < 128) s_x2j[tid] = sqn[b*NPTS + j0 + tid];
    __syncthreads();   // staging done (covers xq at t=0; prev scan done via loop-end barrier)

    f32x4 acc[2][8];
    #pragma unroll
    for (int mt=0;mt<2;++mt)
      #pragma unroll
      for (int nt=0;nt<8;++nt) acc[mt][nt] = (f32x4){0.f,0.f,0.f,0.f};

    #pragma unroll
    for (int kc=0;kc<2;++kc){
      const int ko = kc*32 + kg*8;
      bf16x8s ah[2], al[2];
      #pragma unroll
      for (int mt=0;mt<2;++mt){
        int q = w*32 + mt*16 + lm;
        ah[mt] = *(const bf16x8s*)&xq[q*72 + ko];
        al[mt] = *(const bf16x8s*)&xq[9216 + q*72 + ko];
      }
      #pragma unroll
      for (int nt=0;nt<8;++nt){
        int n = nt*16 + lm;
        bf16x8s bh = *(const bf16x8s*)&xj[n*72 + ko];
        bf16x8s bl = *(const bf16x8s*)&xj[9216 + n*72 + ko];
        #pragma unroll
        for (int mt=0;mt<2;++mt){
          acc[mt][nt] = __builtin_amdgcn_mfma_f32_16x16x32_bf16(ah[mt], bh, acc[mt][nt], 0,0,0);
          acc[mt][nt] = __builtin_amdgcn_mfma_f32_16x16x32_bf16(ah[mt], bl, acc[mt][nt], 0,0,0);
          acc[mt][nt] = __builtin_amdgcn_mfma_f32_16x16x32_bf16(al[mt], bh, acc[mt][nt], 0,0,0);
        }
      }
    }
    __syncthreads();   // xj reads done; uni becomes dch

    #pragma unroll
    for (int h=0; h<2; ++h) {
      // epilogue: write distance chunk h (cols 64h..64h+63 of the 128-j tile)
      #pragma unroll
      for (int mt=0;mt<2;++mt){
        #pragma unroll
        for (int ntl=0;ntl<4;++ntl){
          int nt = h*4 + ntl;
          f32x4 c = acc[mt][nt];
          int colc = ntl*16 + lm;
          float xj2 = s_x2j[h*64 + colc];
          #pragma unroll
          for (int r=0;r<4;++r){
            int qrow = w*32 + mt*16 + kg*4 + r;
            dch[qrow*68 + colc] = s_x2q[qrow] + xj2 - 2.0f*c[r];
          }
        }
      }
      __syncthreads();
      // scan chunk h: thread (tq,th) scans its 32-col stripe
      {
        const int jb0 = j0 + h*64 + th*32;
        #pragma unroll
        for (int c4=0;c4<8;++c4){
          float4 dv = *(const float4*)&dch[tq*68 + th*32 + c4*4];
          int jj = jb0 + c4*4;
          ins10(bk, dkey(dv.x, jj));
          ins10(bk, dkey(dv.y, jj+1));
          ins10(bk, dkey(dv.z, jj+2));
          ins10(bk, dkey(dv.w, jj+3));
        }
      }
      __syncthreads();
    }
  }

  // in-block merge of 2 per-thread lists per query
  #pragma unroll
  for (int u=0;u<10;++u) lst[tq*20 + th*10 + u] = bk[u];
  __syncthreads();
  if (tid < 128) {
    const unsigned long long* row = &lst[tid*20];
    int ia=0, ib=0;
    size_t base = ((size_t)jh*(4*NPTS) + (size_t)b*NPTS + q0 + tid)*10;
    #pragma unroll
    for (int u=0;u<10;++u){
      unsigned long long ka = row[ia], kb2 = row[10+ib];
      bool ta = ka < kb2;
      pu[base+u] = ta ? ka : kb2;
      ia += ta ? 1 : 0; ib += ta ? 0 : 1;
    }
  }
}

// ---------- KNN for conv1 (C=4, fp32 VALU GEMM, exact self-dist) ----------
__global__ __launch_bounds__(256, 2) void knn4_kernel(const float* __restrict__ X,
                                                      const float* __restrict__ sqn,
                                                      unsigned long long* __restrict__ pu){
  __shared__ __align__(16) float xqT[4*132];
  __shared__ __align__(16) float uni[10752];   // xjT[4][132] | dch[128][68] | lists
  __shared__ float s_x2q[128];
  __shared__ float s_x2j[128];

  const int b   = blockIdx.y;
  const int q0  = blockIdx.x * 128;
  const int jh  = blockIdx.z;
  const int tid = threadIdx.x;
  const int tn  = tid & 15;
  const int tm  = tid >> 4;
  const int tq  = tid & 127;
  const int th  = tid >> 7;

  const float* Xb = X + (size_t)b * NPTS * 4;

  for (int i = tid; i < 128; i += 256) {
    float4 v = *(const float4*)(Xb + (size_t)(q0+i)*4);
    xqT[0*132+i] = v.x; xqT[1*132+i] = v.y; xqT[2*132+i] = v.z; xqT[3*132+i] = v.w;
  }
  if (tid < 128) s_x2q[tid] = sqn[b*NPTS + q0 + tid];

  const int sw  = ((tn>>2)&3) << 2;
  const int bp0 = (tn*8)     ^ sw;
  const int bp1 = (tn*8 + 4) ^ sw;

  unsigned long long bk[10];
  #pragma unroll
  for (int u=0;u<10;++u) bk[u] = ~0ULL;

  for (int t = 0; t < 32; ++t) {
    const int j0 = jh*4096 + t*128;
    __syncthreads();
    for (int i = tid; i < 128; i += 256) {
      float4 v = *(const float4*)(Xb + (size_t)(j0+i)*4);
      int pj = i ^ (((i>>5)&3) << 2);
      uni[0*132+pj] = v.x; uni[1*132+pj] = v.y; uni[2*132+pj] = v.z; uni[3*132+pj] = v.w;
    }
    if (tid < 128) s_x2j[tid] = sqn[b*NPTS + j0 + tid];
    __syncthreads();

    float acc[8][8];
    #pragma unroll
    for (int i=0;i<8;++i)
      #pragma unroll
      for (int j=0;j<8;++j) acc[i][j] = 0.f;

    #pragma unroll
    for (int kk=0; kk<4; ++kk) {
      float av[8], bv[8];
      *(float4*)&av[0] = *(const float4*)&xqT[kk*132 + tm*8];
      *(float4*)&av[4] = *(const float4*)&xqT[kk*132 + tm*8 + 4];
      *(float4*)&bv[0] = *(const float4*)&uni[kk*132 + bp0];
      *(float4*)&bv[4] = *(const float4*)&uni[kk*132 + bp1];
      #pragma unroll
      for (int i=0;i<8;++i)
        #pragma unroll
        for (int j=0;j<8;++j)
          acc[i][j] = fmaf(av[i], bv[j], acc[i][j]);
    }
    __syncthreads();  // gemm reads done; uni becomes dch[128][68]

    #pragma unroll
    for (int h=0; h<2; ++h) {
      #pragma unroll
      for (int qi=0; qi<8; ++qi) {
        const int row = tm*8 + qi;
        const float xq2 = s_x2q[row];
        const int jr = (h + tm) & 1;   // bank rotation (write order only)
        const int hh = h ^ ((tm) & 1) ^ h; (void)hh;
        // keep R3 semantics: chunk h holds cols tn*4.. for j = tn*8 + h*4 + u
        float4 v;
        v.x = xq2 + s_x2j[tn*8 + h*4 + 0] - 2.f*acc[qi][h*4+0];
        v.y = xq2 + s_x2j[tn*8 + h*4 + 1] - 2.f*acc[qi][h*4+1];
        v.z = xq2 + s_x2j[tn*8 + h*4 + 2] - 2.f*acc[qi][h*4+2];
        v.w = xq2 + s_x2j[tn*8 + h*4 + 3] - 2.f*acc[qi][h*4+3];
        *(float4*)&uni[row*68 + tn*4] = v;
      }
      __syncthreads();
      {
        #pragma unroll
        for (int w4=0; w4<8; ++w4) {
          const int c4 = th*32 + w4*4;
          float4 dv = *(const float4*)&uni[tq*68 + c4];
          const int jb = j0 + (c4>>2)*8 + h*4;
          ins10(bk, dkey(dv.x, jb));
          ins10(bk, dkey(dv.y, jb+1));
          ins10(bk, dkey(dv.z, jb+2));
          ins10(bk, dkey(dv.w, jb+3));
        }
      }
      __syncthreads();
    }
  }

  unsigned long long* lst = (unsigned long long*)uni;
  #pragma unroll
  for (int u=0;u<10;++u) lst[tq*20 + th*10 + u] = bk[u];
  __syncthreads();
  if (tid < 128) {
    const unsigned long long* row = &lst[tid*20];
    int ia=0, ib=0;
    size_t base = ((size_t)jh*(4*NPTS) + (size_t)b*NPTS + q0 + tid)*10;
    #pragma unroll
    for (int u=0;u<10;++u){
      unsigned long long ka = row[ia], kb2 = row[10+ib];
      bool ta = ka < kb2;
      pu[base+u] = ta ? ka : kb2;
      ia += ta ? 1 : 0; ib += ta ? 0 : 1;
    }
  }
}

// ---------- merge the 2 j-half partial u64 lists -> final idx ----------
__global__ __launch_bounds__(256) void knnmerge_kernel(const unsigned long long* __restrict__ pu,
                                                       int* __restrict__ idxout){
  int p = blockIdx.x*256 + threadIdx.x;   // 0..32767
  const unsigned long long* A = pu + (size_t)p*10;
  const unsigned long long* B = pu + (size_t)(4*NPTS)*10 + (size_t)p*10;
  int ia=0, ib=0;
  int* op = idxout + (size_t)p*10;
  #pragma unroll
  for (int u=0;u<10;++u){
    unsigned long long ka = A[ia], kb = B[ib];
    bool t = ka < kb;
    op[u] = (int)((t ? ka : kb) & 0xFFFFFFFFULL);
    ia += t ? 1 : 0; ib += t ? 0 : 1;
  }
}

// ---------- prep U/D for 64-ch edge conv: U = X@W[0:64], D = X@(W[64:128]-W[0:64]) ----------
__global__ __launch_bounds__(256) void prepUD64_kernel(const float* __restrict__ XC, int cin,
                                                       const float* __restrict__ W,
                                                       float* __restrict__ U,
                                                       float* __restrict__ D){
  int p = blockIdx.x*256 + threadIdx.x;
  float x[64];
  {
    const float4* xr = (const float4*)(XC + (size_t)p*192 + cin);
    #pragma unroll
    for (int c4=0;c4<16;++c4){
      float4 v = xr[c4];
      x[c4*4]=v.x; x[c4*4+1]=v.y; x[c4*4+2]=v.z; x[c4*4+3]=v.w;
    }
  }
  const float4* W4 = (const float4*)W;
  float4 z[16];
  #pragma unroll
  for (int o=0;o<16;++o) z[o] = make_float4(0,0,0,0);
  #pragma unroll
  for (int c=0;c<64;++c) {
    const float xc = x[c];
    #pragma unroll
    for (int o=0;o<16;++o) z[o] = f4fma(xc, W4[c*16+o], z[o]);
  }
  float4* up = (float4*)(U + (size_t)p*64);
  #pragma unroll
  for (int o=0;o<16;++o) up[o] = z[o];
  #pragma unroll
  for (int o=0;o<16;++o) z[o] = make_float4(0,0,0,0);
  #pragma unroll
  for (int c=0;c<64;++c) {
    const float xc = x[c];
    #pragma unroll
    for (int o=0;o<16;++o) {
      float4 wt = W4[c*16+o], wb = W4[(64+c)*16+o];
      float4 wd = make_float4(wb.x-wt.x, wb.y-wt.y, wb.z-wt.z, wb.w-wt.w);
      z[o] = f4fma(xc, wd, z[o]);
    }
  }
  float4* dp = (float4*)(D + (size_t)p*64);
  #pragma unroll
  for (int o=0;o<16;++o) dp[o] = z[o];
}

// ---------- prep U/D for conv1 (targets, 12-ch edge feats collapse to 3) ----------
__global__ __launch_bounds__(256) void prepUD12_kernel(const float* __restrict__ T,
                                                       const float* __restrict__ W1,
                                                       float* __restrict__ U,
                                                       float* __restrict__ D){
  int p = blockIdx.x*256 + threadIdx.x;
  float t[3] = {T[p*3+0], T[p*3+1], T[p*3+2]};
  const float4* W = (const float4*)W1;
  float4 u[16], q[16];
  #pragma unroll
  for (int o=0;o<16;++o){ u[o]=make_float4(0,0,0,0); q[o]=make_float4(0,0,0,0); }
  #pragma unroll
  for (int c=0;c<3;++c){
    const float tc = t[c];
    #pragma unroll
    for (int o=0;o<16;++o){
      float4 ws  = W[c*16+o],     ws2 = W[(c+3)*16+o];
      float4 wq  = W[(c+6)*16+o], wq2 = W[(c+9)*16+o];
      u[o] = f4fma(tc, make_float4(ws.x+ws2.x, ws.y+ws2.y, ws.z+ws2.z, ws.w+ws2.w), u[o]);
      q[o] = f4fma(tc, make_float4(wq.x+wq2.x, wq.y+wq2.y, wq.z+wq2.z, wq.w+wq2.w), q[o]);
    }
  }
  float4* up = (float4*)(U + (size_t)p*64);
  float4* dp = (float4*)(D + (size_t)p*64);
  #pragma unroll
  for (int o=0;o<16;++o){
    up[o] = u[o];
    dp[o] = make_float4(q[o].x-u[o].x, q[o].y-u[o].y, q[o].z-u[o].z, q[o].w-u[o].w);
  }
}

// ---------- two-layer edge conv: max_k prelu( prelu(U[nb]+D[p]) @ Wb ) ----------
__global__ __launch_bounds__(256) void edge2_kernel(const float* __restrict__ U,
                                                    const float* __restrict__ Dp,
                                                    const int* __restrict__ idx,
                                                    const float* __restrict__ Wb,
                                                    const float* __restrict__ PA, int paa, int pab,
                                                    float* __restrict__ out, int coff){
  __shared__ __align__(16) float sW[64][68];
  const int tid = threadIdx.x;
  for (int i = tid; i < 1024; i += 256) {
    float4 w = *(const float4*)(Wb + (size_t)i*4);
    *(float4*)&sW[i>>4][(i&15)*4] = w;
  }
  const int t = blockIdx.x*256 + tid;
  const int q4 = t & 3, p = t >> 2, b = p >> 13;
  const float aa = PA[paa], ab = PA[pab];
  float dv[64];
  {
    const float4* dr = (const float4*)(Dp + (size_t)p*64);
    #pragma unroll
    for (int i=0;i<16;++i){
      float4 v = dr[i];
      dv[i*4]=v.x; dv[i*4+1]=v.y; dv[i*4+2]=v.z; dv[i*4+3]=v.w;
    }
  }
  __syncthreads();
  float4 mx[4];
  #pragma unroll
  for (int o=0;o<4;++o) mx[o] = make_float4(-INFINITY,-INFINITY,-INFINITY,-INFINITY);
  for (int k=0;k<10;++k) {
    int nb = idx[p*10+k];
    const float4* ur = (const float4*)(U + ((size_t)(b<<13)+nb)*64);
    float4 z[4];
    #pragma unroll
    for (int o=0;o<4;++o) z[o] = make_float4(0,0,0,0);
    #pragma unroll
    for (int c4=0;c4<16;++c4) {
      float4 uv = ur[c4];
      float h0 = preluf(uv.x + dv[c4*4+0], aa);
      float h1 = preluf(uv.y + dv[c4*4+1], aa);
      float h2 = preluf(uv.z + dv[c4*4+2], aa);
      float h3 = preluf(uv.w + dv[c4*4+3], aa);
      #pragma unroll
      for (int o=0;o<4;++o) {
        z[o] = f4fma(h0, *(const float4*)&sW[c4*4+0][q4*16+o*4], z[o]);
        z[o] = f4fma(h1, *(const float4*)&sW[c4*4+1][q4*16+o*4], z[o]);
        z[o] = f4fma(h2, *(const float4*)&sW[c4*4+2][q4*16+o*4], z[o]);
        z[o] = f4fma(h3, *(const float4*)&sW[c4*4+3][q4*16+o*4], z[o]);
      }
    }
    #pragma unroll
    for (int o=0;o<4;++o) {
      mx[o].x = fmaxf(mx[o].x, preluf(z[o].x, ab));
      mx[o].y = fmaxf(mx[o].y, preluf(z[o].y, ab));
      mx[o].z = fmaxf(mx[o].z, preluf(z[o].z, ab));
      mx[o].w = fmaxf(mx[o].w, preluf(z[o].w, ab));
    }
  }
  float4* op = (float4*)(out + (size_t)p*192 + coff + q4*16);
  #pragma unroll
  for (int o=0;o<4;++o) op[o] = mx[o];
}

// ---------- single-layer edge conv (conv3): max_k prelu(U[nb]+D[p]) ----------
__global__ __launch_bounds__(256) void edge1max_kernel(const float* __restrict__ U,
                                                       const float* __restrict__ Dp,
                                                       const int* __restrict__ idx,
                                                       const float* __restrict__ PA, int paa,
                                                       float* __restrict__ out, int coff){
  const int t = blockIdx.x*256 + threadIdx.x;
  const int hf = t & 1, p = t >> 1, b = p >> 13;
  const float aa = PA[paa];
  float dv[32];
  {
    const float4* dr = (const float4*)(Dp + (size_t)p*64 + hf*32);
    #pragma unroll
    for (int i=0;i<8;++i){
      float4 v = dr[i];
      dv[i*4]=v.x; dv[i*4+1]=v.y; dv[i*4+2]=v.z; dv[i*4+3]=v.w;
    }
  }
  float mx[32];
  #pragma unroll
  for (int o=0;o<32;++o) mx[o] = -INFINITY;
  for (int k=0;k<10;++k) {
    int nb = idx[p*10+k];
    const float4* ur = (const float4*)(U + ((size_t)(b<<13)+nb)*64 + hf*32);
    #pragma unroll
    for (int i=0;i<8;++i) {
      float4 v = ur[i];
      mx[i*4+0] = fmaxf(mx[i*4+0], preluf(v.x + dv[i*4+0], aa));
      mx[i*4+1] = fmaxf(mx[i*4+1], preluf(v.y + dv[i*4+1], aa));
      mx[i*4+2] = fmaxf(mx[i*4+2], preluf(v.z + dv[i*4+2], aa));
      mx[i*4+3] = fmaxf(mx[i*4+3], preluf(v.w + dv[i*4+3], aa));
    }
  }
  float4* op = (float4*)(out + (size_t)p*192 + coff + hf*32);
  #pragma unroll
  for (int i=0;i<8;++i) op[i] = make_float4(mx[i*4],mx[i*4+1],mx[i*4+2],mx[i*4+3]);
}

// ---------- tiled fp32 GEMM: C = prelu(A@B [+bias]) ; EPI2: column-max partials ----------
template<int EPI>
__global__ __launch_bounds__(256) void gemm_kernel(const float* __restrict__ A, int lda,
                                                   const float* __restrict__ Bm, int ldb,
                                                   float* __restrict__ C, int ldc,
                                                   const float* __restrict__ bias,
                                                   const float* __restrict__ PA, int pidx,
                                                   int K, int Ntot){
  __shared__ __align__(16) float As[16][132];
  __shared__ __align__(16) float Bs[16][132];
  const int tid = threadIdx.x;
  const int m0 = blockIdx.x*128, n0 = blockIdx.y*128;
  const int tm = tid & 15, tn = tid >> 4;
  float acc[8][8];
  #pragma unroll
  for (int i=0;i<8;++i)
    #pragma unroll
    for (int j=0;j<8;++j) acc[i][j]=0.f;

  for (int k0=0;k0<K;k0+=16) {
    {
      int r = tid >> 2, kq = (tid&3)*4;
      #pragma unroll
      for (int it=0; it<2; ++it) {
        int rr = r + it*64;
        float4 v = *(const float4*)(A + (size_t)(m0+rr)*lda + k0 + kq);
        As[kq+0][rr]=v.x; As[kq+1][rr]=v.y; As[kq+2][rr]=v.z; As[kq+3][rr]=v.w;
      }
    }
    {
      int kk = tid >> 4, c = (tid&15)*8;
      const float* bp = Bm + (size_t)(k0+kk)*ldb + n0 + c;
      *(float4*)&Bs[kk][c]   = *(const float4*)bp;
      *(float4*)&Bs[kk][c+4] = *(const float4*)(bp+4);
    }
    __syncthreads();
    #pragma unroll
    for (int kk=0;kk<16;++kk) {
      float av[8], bv[8];
      *(float4*)&av[0] = *(const float4*)&As[kk][tm*8+0];
      *(float4*)&av[4] = *(const float4*)&As[kk][tm*8+4];
      *(float4*)&bv[0] = *(const float4*)&Bs[kk][tn*8+0];
      *(float4*)&bv[4] = *(const float4*)&Bs[kk][tn*8+4];
      #pragma unroll
      for (int i=0;i<8;++i)
        #pragma unroll
        for (int j=0;j<8;++j)
          acc[i][j] = fmaf(av[i], bv[j], acc[i][j]);
    }
    __syncthreads();
  }
  const float a = PA[pidx];
  if (EPI == 2) {
    #pragma unroll
    for (int j=0;j<8;++j) {
      float m = -INFINITY;
      #pragma unroll
      for (int i=0;i<8;++i) { float v = acc[i][j]; v = v>=0.f? v : a*v; m = fmaxf(m,v); }
      #pragma unroll
      for (int off=1;off<16;off<<=1) m = fmaxf(m, __shfl_xor(m, off));
      if (tm == 0) C[(size_t)blockIdx.x*Ntot + n0 + tn*8 + j] = m;
    }
  } else {
    float bcol[8];
    if (EPI==1) {
      int bb = m0 >> 13;
      #pragma unroll
      for (int j=0;j<8;++j) bcol[j] = bias[bb*256 + n0 + tn*8 + j];
    }
    #pragma unroll
    for (int i=0;i<8;++i) {
      float out[8];
      #pragma unroll
      for (int j=0;j<8;++j) {
        float v = acc[i][j] + (EPI==1 ? bcol[j] : 0.f);
        out[j] = v>=0.f? v : a*v;
      }
      float* cp = C + (size_t)(m0 + tm*8 + i)*ldc + n0 + tn*8;
      *(float4*)cp     = make_float4(out[0],out[1],out[2],out[3]);
      *(float4*)(cp+4) = make_float4(out[4],out[5],out[6],out[7]);
    }
  }
}

__global__ __launch_bounds__(256) void reduce_pmax(const float* __restrict__ pmax,
                                                   float* __restrict__ x5m){
  int t = blockIdx.x*256 + threadIdx.x;
  if (t < 4096) {
    int b = t >> 10, o = t & 1023;
    float m = -INFINITY;
    for (int mt=0; mt<64; ++mt) m = fmaxf(m, pmax[((size_t)(b*64+mt))*1024 + o]);
    x5m[t] = m;
  }
}

__global__ __launch_bounds__(256) void bias7_kernel(const float* __restrict__ x5m,
                                                    const float* __restrict__ W7,
                                                    float* __restrict__ b7){
  int b = blockIdx.x; int o = threadIdx.x;
  float s = 0.f;
  for (int j=0;j<1024;++j) s = fmaf(x5m[b*1024+j], W7[(size_t)(192+j)*256 + o], s);
  b7[b*256+o] = s;
}

__global__ __launch_bounds__(256) void final10_kernel(const float* __restrict__ y3,
                                                      const float* __restrict__ W10,
                                                      const float* __restrict__ PA,
                                                      float* __restrict__ out){
  int p = blockIdx.x*256 + threadIdx.x;
  const float4* r = (const float4*)(y3 + (size_t)p*128);
  float s0=0.f, s1=0.f;
  #pragma unroll
  for (int c4=0;c4<32;++c4){
    float4 v = r[c4];
    s0 = fmaf(v.x, W10[(c4*4+0)*2+0], s0); s1 = fmaf(v.x, W10[(c4*4+0)*2+1], s1);
    s0 = fmaf(v.y, W10[(c4*4+1)*2+0], s0); s1 = fmaf(v.y, W10[(c4*4+1)*2+1], s1);
    s0 = fmaf(v.z, W10[(c4*4+2)*2+0], s0); s1 = fmaf(v.z, W10[(c4*4+2)*2+1], s1);
    s0 = fmaf(v.w, W10[(c4*4+3)*2+0], s0); s1 = fmaf(v.w, W10[(c4*4+3)*2+1], s1);
  }
  float a = PA[9];
  out[p*2+0] = s0>=0.f? s0 : a*s0;
  out[p*2+1] = s1>=0.f? s1 : a*s1;
}

extern "C" void kernel_launch(void* const* d_in, const int* in_sizes, int n_in,
                              void* d_out, int out_size, void* d_ws, size_t ws_size,
                              hipStream_t stream) {
  const float* T   = (const float*)d_in[0];
  const float* W1  = (const float*)d_in[1];
  const float* W2  = (const float*)d_in[2];
  const float* W3  = (const float*)d_in[3];
  const float* W4  = (const float*)d_in[4];
  const float* W5  = (const float*)d_in[5];
  const float* W6  = (const float*)d_in[6];
  const float* W7  = (const float*)d_in[7];
  const float* W8  = (const float*)d_in[8];
  const float* W9  = (const float*)d_in[9];
  const float* W10 = (const float*)d_in[10];
  const float* PA  = (const float*)d_in[11];

  float* ws   = (float*)d_ws;
  float* x0   = ws + 0;                // 131072
  float* sqn0 = ws + 131072;           // 32768
  float* sqn1 = ws + 163840;           // 32768
  float* sqn2 = ws + 196608;           // 32768
  int*   idx0 = (int*)(ws + 229376);   // 327680
  int*   idx1 = (int*)(ws + 557056);   // 327680
  int*   idx2 = (int*)(ws + 884736);   // 327680
  float* xcat = ws + 1212416;          // 6291456  [B,N,192]
  float* pmax = ws + 7503872;          // 262144
  float* x5m  = ws + 7766016;          // 4096
  float* b7   = ws + 7770112;          // 1024
  float* y1   = ws + 7771136;          // 8388608  (aliased: U / knn u64 partials)
  float* y2   = ws + 16159744;         // 8388608  (aliased: D)
  float* y3   = xcat;
  float* U    = y1;
  float* D    = y2;
  unsigned long long* pu = (unsigned long long*)y1;  // [2][32768][10] u64 = 5.24 MB

  // conv1
  prep0_kernel<<<128, 256, 0, stream>>>(T, x0, sqn0);
  knn4_kernel<<<dim3(64,4,2), 256, 0, stream>>>(x0, sqn0, pu);
  knnmerge_kernel<<<128, 256, 0, stream>>>(pu, idx0);
  prepUD12_kernel<<<128, 256, 0, stream>>>(T, W1, U, D);
  edge2_kernel<<<512, 256, 0, stream>>>(U, D, idx0, W2, PA, 0, 1, xcat, 0);

  // conv2
  sqnorm_kernel<<<128, 256, 0, stream>>>(xcat, 0, sqn1);
  knn64_kernel<<<dim3(64,4,2), 256, 0, stream>>>(xcat, 192, 0, sqn1, pu);
  knnmerge_kernel<<<128, 256, 0, stream>>>(pu, idx1);
  prepUD64_kernel<<<128, 256, 0, stream>>>(xcat, 0, W3, U, D);
  edge2_kernel<<<512, 256, 0, stream>>>(U, D, idx1, W4, PA, 2, 3, xcat, 64);

  // conv3
  sqnorm_kernel<<<128, 256, 0, stream>>>(xcat, 64, sqn2);
  knn64_kernel<<<dim3(64,4,2), 256, 0, stream>>>(xcat, 192, 64, sqn2, pu);
  knnmerge_kernel<<<128, 256, 0, stream>>>(pu, idx2);
  prepUD64_kernel<<<128, 256, 0, stream>>>(xcat, 64, W5, U, D);
  edge1max_kernel<<<256, 256, 0, stream>>>(U, D, idx2, PA, 4, xcat, 128);

  // head
  gemm_kernel<2><<<dim3(256,8), 256, 0, stream>>>(xcat, 192, W6, 1024, pmax, 0, nullptr, PA, 5, 192, 1024);
  reduce_pmax<<<16, 256, 0, stream>>>(pmax, x5m);
  bias7_kernel<<<4, 256, 0, stream>>>(x5m, W7, b7);
  gemm_kernel<1><<<dim3(256,2), 256, 0, stream>>>(xcat, 192, W7, 256, y1, 256, b7, PA, 6, 192, 256);
  gemm_kernel<0><<<dim3(256,2), 256, 0, stream>>>(y1, 256, W8, 256, y2, 256, nullptr, PA, 7, 256, 256);
  gemm_kernel<0><<<dim3(256,1), 256, 0, stream>>>(y2, 256, W9, 128, y3, 128, nullptr, PA, 8, 256, 128);
  final10_kernel<<<128, 256, 0, stream>>>(y3, W10, PA, (float*)d_out);
}

// Round 5
// 2311.096 us; speedup vs baseline: 3.4324x; 1.7485x over previous
//
#include <hip/hip_runtime.h>
#include <math.h>

#define NPTS 8192
#define KNNK 10

typedef __attribute__((ext_vector_type(8))) short bf16x8s;
typedef __attribute__((ext_vector_type(4))) float f32x4;

__device__ __forceinline__ float preluf(float v, float a){ return v >= 0.f ? v : a*v; }
__device__ __forceinline__ float4 f4fma(float a, float4 b, float4 c){
  return make_float4(fmaf(a,b.x,c.x), fmaf(a,b.y,c.y), fmaf(a,b.z,c.z), fmaf(a,b.w,c.w));
}

// stable strict-less insert of (d,j) into ascending sorted-10 (f32 keys).
// Valid for lex-(d,j) order ONLY when each thread's stream is ascending in j.
// Body is a no-op for lanes with d >= bd[9], so wave-uniform execution is safe.
__device__ __forceinline__ void kins(float* bd, int* bi, float d, int j){
  if (__any(d < bd[9])) {
    float td = d; int ti = j;
    #pragma unroll
    for (int s=0;s<10;++s){
      bool c = td < bd[s];
      float dn = c ? td : bd[s];
      float dx = c ? bd[s] : td;
      int   in2 = c ? ti : bi[s];
      int   ix  = c ? bi[s] : ti;
      bd[s] = dn; bi[s] = in2; td = dx; ti = ix;
    }
  }
}

// split float into bf16 hi/lo (rne); returns packed hi pair, sets lo pair
__device__ __forceinline__ unsigned bfsplit2(float a, float b, unsigned& lo2){
  unsigned ua = __float_as_uint(a), ub = __float_as_uint(b);
  unsigned ha = (ua + 0x7FFFu + ((ua>>16)&1u)) & 0xFFFF0000u;
  unsigned hb = (ub + 0x7FFFu + ((ub>>16)&1u)) & 0xFFFF0000u;
  float ra = a - __uint_as_float(ha);
  float rb = b - __uint_as_float(hb);
  unsigned la = __float_as_uint(ra), lb = __float_as_uint(rb);
  unsigned qa = (la + 0x7FFFu + ((la>>16)&1u)) >> 16;
  unsigned qb = (lb + 0x7FFFu + ((lb>>16)&1u)) & 0xFFFF0000u;
  lo2 = qa | qb;
  return (ha >> 16) | hb;
}

// ---------- prep: x0pad (targets padded to 4ch) + sqnorm ----------
__global__ __launch_bounds__(256) void prep0_kernel(const float* __restrict__ T,
                                                    float* __restrict__ x0,
                                                    float* __restrict__ sqn){
  int p = blockIdx.x*256 + threadIdx.x;
  float t0 = T[p*3+0], t1 = T[p*3+1], t2 = T[p*3+2];
  *(float4*)(x0 + (size_t)p*4) = make_float4(t0,t1,t2,0.f);
  float s = fmaf(t0,t0,0.f); s = fmaf(t1,t1,s); s = fmaf(t2,t2,s); s = fmaf(0.f,0.f,s);
  sqn[p] = s;
}

__global__ __launch_bounds__(256) void sqnorm_kernel(const float* __restrict__ XC, int cin,
                                                     float* __restrict__ sqn){
  int p = blockIdx.x*256 + threadIdx.x;
  const float4* r = (const float4*)(XC + (size_t)p*192 + cin);
  float s = 0.f;
  #pragma unroll
  for (int c4=0;c4<16;++c4){
    float4 v = r[c4];
    s = fmaf(v.x,v.x,s); s = fmaf(v.y,v.y,s); s = fmaf(v.z,v.z,s); s = fmaf(v.w,v.w,s);
  }
  sqn[p] = s;
}

// ---------- KNN for C=64 features: MFMA bf16 hi/lo distance GEMM + f32 top-10 ----------
__global__ __launch_bounds__(256, 2) void knn64_kernel(const float* __restrict__ X, int ldx, int coff,
                                                       const float* __restrict__ sqn,
                                                       float* __restrict__ pd, int* __restrict__ pi){
  __shared__ __align__(16) unsigned short xq[2*128*72];  // [hilo][q][72] bf16 bits
  __shared__ __align__(16) unsigned char uni[36864];     // xj bf16 | dch[128][68] f32 | lists
  __shared__ float s_x2q[128];
  __shared__ float s_x2j[128];

  unsigned short* xj = (unsigned short*)uni;
  float* dch = (float*)uni;
  float* lstd = (float*)uni;                 // [128][20]
  int*   lsti = (int*)(uni + 10240);         // [128][20]

  const int b   = blockIdx.y;
  const int q0  = blockIdx.x * 128;
  const int jh  = blockIdx.z;
  const int tid = threadIdx.x;
  const int L   = tid & 63;
  const int w   = tid >> 6;
  const int lm  = L & 15;
  const int kg  = L >> 4;
  const int tq  = tid & 127;
  const int th  = tid >> 7;

  const float* Xb = X + (size_t)b * NPTS * ldx + coff;

  // stage queries (hi/lo bf16), once
  #pragma unroll
  for (int s=0;s<8;++s){
    int e = tid + s*256;
    int r = e >> 4, c4 = (e & 15) << 2;
    float4 v = *(const float4*)(Xb + (size_t)(q0+r)*ldx + c4);
    unsigned lo01, lo23;
    unsigned hi01 = bfsplit2(v.x, v.y, lo01);
    unsigned hi23 = bfsplit2(v.z, v.w, lo23);
    uint2 hp; hp.x = hi01; hp.y = hi23;
    uint2 lp; lp.x = lo01; lp.y = lo23;
    *(uint2*)&xq[r*72 + c4]        = hp;
    *(uint2*)&xq[9216 + r*72 + c4] = lp;
  }
  if (tid < 128) s_x2q[tid] = sqn[b*NPTS + q0 + tid];

  float bd[10]; int bi[10];
  #pragma unroll
  for (int u=0;u<10;++u){ bd[u] = INFINITY; bi[u] = 0x7fffffff; }

  for (int t = 0; t < 32; ++t) {
    const int j0 = jh*4096 + t*128;
    #pragma unroll
    for (int s=0;s<8;++s){
      int e = tid + s*256;
      int r = e >> 4, c4 = (e & 15) << 2;
      float4 v = *(const float4*)(Xb + (size_t)(j0+r)*ldx + c4);
      unsigned lo01, lo23;
      unsigned hi01 = bfsplit2(v.x, v.y, lo01);
      unsigned hi23 = bfsplit2(v.z, v.w, lo23);
      uint2 hp; hp.x = hi01; hp.y = hi23;
      uint2 lp; lp.x = lo01; lp.y = lo23;
      *(uint2*)&xj[r*72 + c4]        = hp;
      *(uint2*)&xj[9216 + r*72 + c4] = lp;
    }
    if (tid < 128) s_x2j[tid] = sqn[b*NPTS + j0 + tid];
    __syncthreads();

    f32x4 acc[2][8];
    #pragma unroll
    for (int mt=0;mt<2;++mt)
      #pragma unroll
      for (int nt=0;nt<8;++nt) acc[mt][nt] = (f32x4){0.f,0.f,0.f,0.f};

    #pragma unroll
    for (int kc=0;kc<2;++kc){
      const int ko = kc*32 + kg*8;
      bf16x8s ah[2], al[2];
      #pragma unroll
      for (int mt=0;mt<2;++mt){
        int q = w*32 + mt*16 + lm;
        ah[mt] = *(const bf16x8s*)&xq[q*72 + ko];
        al[mt] = *(const bf16x8s*)&xq[9216 + q*72 + ko];
      }
      #pragma unroll
      for (int nt=0;nt<8;++nt){
        int n = nt*16 + lm;
        bf16x8s bh = *(const bf16x8s*)&xj[n*72 + ko];
        bf16x8s bl = *(const bf16x8s*)&xj[9216 + n*72 + ko];
        #pragma unroll
        for (int mt=0;mt<2;++mt){
          acc[mt][nt] = __builtin_amdgcn_mfma_f32_16x16x32_bf16(ah[mt], bh, acc[mt][nt], 0,0,0);
          acc[mt][nt] = __builtin_amdgcn_mfma_f32_16x16x32_bf16(ah[mt], bl, acc[mt][nt], 0,0,0);
          acc[mt][nt] = __builtin_amdgcn_mfma_f32_16x16x32_bf16(al[mt], bh, acc[mt][nt], 0,0,0);
        }
      }
    }
    __syncthreads();   // xj reads done; uni becomes dch

    #pragma unroll
    for (int h=0; h<2; ++h) {
      // epilogue: write distance chunk h (cols h*64..h*64+63 of the 128-j tile)
      #pragma unroll
      for (int mt=0;mt<2;++mt){
        #pragma unroll
        for (int ntl=0;ntl<4;++ntl){
          int nt = h*4 + ntl;
          f32x4 c = acc[mt][nt];
          int colc = ntl*16 + lm;
          float xj2 = s_x2j[h*64 + colc];
          #pragma unroll
          for (int r=0;r<4;++r){
            int qrow = w*32 + mt*16 + kg*4 + r;
            dch[qrow*68 + colc] = s_x2q[qrow] + xj2 - 2.0f*c[r];
          }
        }
      }
      __syncthreads();
      // scan chunk h: thread (tq,th) scans its 32-col stripe (ascending j)
      {
        const int jb0 = j0 + h*64 + th*32;
        #pragma unroll
        for (int c4=0;c4<8;++c4){
          float4 dv = *(const float4*)&dch[tq*68 + th*32 + c4*4];
          int jj = jb0 + c4*4;
          kins(bd, bi, dv.x, jj);
          kins(bd, bi, dv.y, jj+1);
          kins(bd, bi, dv.z, jj+2);
          kins(bd, bi, dv.w, jj+3);
        }
      }
      __syncthreads();
    }
  }

  // in-block merge of 2 per-thread lists per query (lex on (d,i))
  #pragma unroll
  for (int u=0;u<10;++u){
    lstd[tq*20 + th*10 + u] = bd[u];
    lsti[tq*20 + th*10 + u] = bi[u];
  }
  __syncthreads();
  if (tid < 128) {
    int ia=0, ib=0;
    size_t base = ((size_t)jh*(4*NPTS) + (size_t)b*NPTS + q0 + tid)*10;
    #pragma unroll
    for (int u=0;u<10;++u){
      float da = lstd[tid*20+ia], db = lstd[tid*20+10+ib];
      int   ja = lsti[tid*20+ia], jb2 = lsti[tid*20+10+ib];
      bool ta = (da < db) || (da == db && ja < jb2);
      pd[base+u] = ta ? da : db;
      pi[base+u] = ta ? ja : jb2;
      ia += ta ? 1 : 0; ib += ta ? 0 : 1;
    }
  }
}

// ---------- KNN for conv1 (C=4, fp32 VALU GEMM, exact self-dist) ----------
__global__ __launch_bounds__(256, 2) void knn4_kernel(const float* __restrict__ X,
                                                      const float* __restrict__ sqn,
                                                      float* __restrict__ pd, int* __restrict__ pi){
  __shared__ __align__(16) float xqT[4*132];
  __shared__ __align__(16) float uni[10752];   // xjT[4][132] | dch[128][68] | lists
  __shared__ float s_x2q[128];
  __shared__ float s_x2j[128];

  const int b   = blockIdx.y;
  const int q0  = blockIdx.x * 128;
  const int jh  = blockIdx.z;
  const int tid = threadIdx.x;
  const int tn  = tid & 15;
  const int tm  = tid >> 4;
  const int tq  = tid & 127;
  const int th  = tid >> 7;

  const float* Xb = X + (size_t)b * NPTS * 4;

  for (int i = tid; i < 128; i += 256) {
    float4 v = *(const float4*)(Xb + (size_t)(q0+i)*4);
    xqT[0*132+i] = v.x; xqT[1*132+i] = v.y; xqT[2*132+i] = v.z; xqT[3*132+i] = v.w;
  }
  if (tid < 128) s_x2q[tid] = sqn[b*NPTS + q0 + tid];

  const int sw  = ((tn>>2)&3) << 2;
  const int bp0 = (tn*8)     ^ sw;
  const int bp1 = (tn*8 + 4) ^ sw;

  float bd[10]; int bi[10];
  #pragma unroll
  for (int u=0;u<10;++u){ bd[u] = INFINITY; bi[u] = 0x7fffffff; }

  for (int t = 0; t < 32; ++t) {
    const int j0 = jh*4096 + t*128;
    __syncthreads();
    for (int i = tid; i < 128; i += 256) {
      float4 v = *(const float4*)(Xb + (size_t)(j0+i)*4);
      int pj = i ^ (((i>>5)&3) << 2);
      uni[0*132+pj] = v.x; uni[1*132+pj] = v.y; uni[2*132+pj] = v.z; uni[3*132+pj] = v.w;
    }
    if (tid < 128) s_x2j[tid] = sqn[b*NPTS + j0 + tid];
    __syncthreads();

    float acc[8][8];
    #pragma unroll
    for (int i=0;i<8;++i)
      #pragma unroll
      for (int j=0;j<8;++j) acc[i][j] = 0.f;

    #pragma unroll
    for (int kk=0; kk<4; ++kk) {
      float av[8], bv[8];
      *(float4*)&av[0] = *(const float4*)&xqT[kk*132 + tm*8];
      *(float4*)&av[4] = *(const float4*)&xqT[kk*132 + tm*8 + 4];
      *(float4*)&bv[0] = *(const float4*)&uni[kk*132 + bp0];
      *(float4*)&bv[4] = *(const float4*)&uni[kk*132 + bp1];
      #pragma unroll
      for (int i=0;i<8;++i)
        #pragma unroll
        for (int j=0;j<8;++j)
          acc[i][j] = fmaf(av[i], bv[j], acc[i][j]);
    }
    __syncthreads();  // gemm reads done; uni becomes dch[128][68]

    // thread owns j = tn*8+u; its chunk h = tn>>3; local col = (tn&7)*8+u
    #pragma unroll
    for (int h=0; h<2; ++h) {
      if ((tn>>3) == h) {
        #pragma unroll
        for (int qi=0; qi<8; ++qi) {
          const int row = tm*8 + qi;
          const float xq2 = s_x2q[row];
          float vv[8];
          #pragma unroll
          for (int u=0;u<8;++u)
            vv[u] = xq2 + s_x2j[tn*8 + u] - 2.f*acc[qi][u];
          *(float4*)&uni[row*68 + (tn&7)*8]     = make_float4(vv[0],vv[1],vv[2],vv[3]);
          *(float4*)&uni[row*68 + (tn&7)*8 + 4] = make_float4(vv[4],vv[5],vv[6],vv[7]);
        }
      }
      __syncthreads();
      {
        const int jb0 = j0 + h*64 + th*32;
        #pragma unroll
        for (int c4=0;c4<8;++c4){
          float4 dv = *(const float4*)&uni[tq*68 + th*32 + c4*4];
          int jj = jb0 + c4*4;
          kins(bd, bi, dv.x, jj);
          kins(bd, bi, dv.y, jj+1);
          kins(bd, bi, dv.z, jj+2);
          kins(bd, bi, dv.w, jj+3);
        }
      }
      __syncthreads();
    }
  }

  float* lstd = uni;             // [128][20]
  int*   lsti = (int*)(uni + 2560);
  #pragma unroll
  for (int u=0;u<10;++u){
    lstd[tq*20 + th*10 + u] = bd[u];
    lsti[tq*20 + th*10 + u] = bi[u];
  }
  __syncthreads();
  if (tid < 128) {
    int ia=0, ib=0;
    size_t base = ((size_t)jh*(4*NPTS) + (size_t)b*NPTS + q0 + tid)*10;
    #pragma unroll
    for (int u=0;u<10;++u){
      float da = lstd[tid*20+ia], db = lstd[tid*20+10+ib];
      int   ja = lsti[tid*20+ia], jb2 = lsti[tid*20+10+ib];
      bool ta = (da < db) || (da == db && ja < jb2);
      pd[base+u] = ta ? da : db;
      pi[base+u] = ta ? ja : jb2;
      ia += ta ? 1 : 0; ib += ta ? 0 : 1;
    }
  }
}

// ---------- merge the 2 j-half partial lists -> final idx ----------
__global__ __launch_bounds__(256) void knnmerge_kernel(const float* __restrict__ pd,
                                                       const int* __restrict__ pi,
                                                       int* __restrict__ idxout){
  int p = blockIdx.x*256 + threadIdx.x;   // 0..32767
  const float* da = pd + (size_t)p*10;
  const float* db = pd + (size_t)(4*NPTS)*10 + (size_t)p*10;
  const int*   ja = pi + (size_t)p*10;
  const int*   jb = pi + (size_t)(4*NPTS)*10 + (size_t)p*10;
  int ia=0, ib=0;
  int* op = idxout + (size_t)p*10;
  #pragma unroll
  for (int u=0;u<10;++u){
    float x = da[ia], y = db[ib];
    int jx = ja[ia], jy = jb[ib];
    bool t = (x < y) || (x == y && jx < jy);
    op[u] = t ? jx : jy;
    ia += t ? 1 : 0; ib += t ? 0 : 1;
  }
}

// ---------- prep U/D for 64-ch edge conv ----------
__global__ __launch_bounds__(256) void prepUD64_kernel(const float* __restrict__ XC, int cin,
                                                       const float* __restrict__ W,
                                                       float* __restrict__ U,
                                                       float* __restrict__ D){
  int p = blockIdx.x*256 + threadIdx.x;
  float x[64];
  {
    const float4* xr = (const float4*)(XC + (size_t)p*192 + cin);
    #pragma unroll
    for (int c4=0;c4<16;++c4){
      float4 v = xr[c4];
      x[c4*4]=v.x; x[c4*4+1]=v.y; x[c4*4+2]=v.z; x[c4*4+3]=v.w;
    }
  }
  const float4* W4 = (const float4*)W;
  float4 z[16];
  #pragma unroll
  for (int o=0;o<16;++o) z[o] = make_float4(0,0,0,0);
  #pragma unroll
  for (int c=0;c<64;++c) {
    const float xc = x[c];
    #pragma unroll
    for (int o=0;o<16;++o) z[o] = f4fma(xc, W4[c*16+o], z[o]);
  }
  float4* up = (float4*)(U + (size_t)p*64);
  #pragma unroll
  for (int o=0;o<16;++o) up[o] = z[o];
  #pragma unroll
  for (int o=0;o<16;++o) z[o] = make_float4(0,0,0,0);
  #pragma unroll
  for (int c=0;c<64;++c) {
    const float xc = x[c];
    #pragma unroll
    for (int o=0;o<16;++o) {
      float4 wt = W4[c*16+o], wb = W4[(64+c)*16+o];
      float4 wd = make_float4(wb.x-wt.x, wb.y-wt.y, wb.z-wt.z, wb.w-wt.w);
      z[o] = f4fma(xc, wd, z[o]);
    }
  }
  float4* dp = (float4*)(D + (size_t)p*64);
  #pragma unroll
  for (int o=0;o<16;++o) dp[o] = z[o];
}

// ---------- prep U/D for conv1 ----------
__global__ __launch_bounds__(256) void prepUD12_kernel(const float* __restrict__ T,
                                                       const float* __restrict__ W1,
                                                       float* __restrict__ U,
                                                       float* __restrict__ D){
  int p = blockIdx.x*256 + threadIdx.x;
  float t[3] = {T[p*3+0], T[p*3+1], T[p*3+2]};
  const float4* W = (const float4*)W1;
  float4 u[16], q[16];
  #pragma unroll
  for (int o=0;o<16;++o){ u[o]=make_float4(0,0,0,0); q[o]=make_float4(0,0,0,0); }
  #pragma unroll
  for (int c=0;c<3;++c){
    const float tc = t[c];
    #pragma unroll
    for (int o=0;o<16;++o){
      float4 ws  = W[c*16+o],     ws2 = W[(c+3)*16+o];
      float4 wq  = W[(c+6)*16+o], wq2 = W[(c+9)*16+o];
      u[o] = f4fma(tc, make_float4(ws.x+ws2.x, ws.y+ws2.y, ws.z+ws2.z, ws.w+ws2.w), u[o]);
      q[o] = f4fma(tc, make_float4(wq.x+wq2.x, wq.y+wq2.y, wq.z+wq2.z, wq.w+wq2.w), q[o]);
    }
  }
  float4* up = (float4*)(U + (size_t)p*64);
  float4* dp = (float4*)(D + (size_t)p*64);
  #pragma unroll
  for (int o=0;o<16;++o){
    up[o] = u[o];
    dp[o] = make_float4(q[o].x-u[o].x, q[o].y-u[o].y, q[o].z-u[o].z, q[o].w-u[o].w);
  }
}

// ---------- two-layer edge conv, wave-per-point: lane = out-channel ----------
// W column in VGPRs; h built cooperatively in LDS (coalesced U gather, read once).
__global__ __launch_bounds__(256) void edge2w_kernel(const float* __restrict__ U,
                                                     const float* __restrict__ Dp,
                                                     const int* __restrict__ idx,
                                                     const float* __restrict__ Wb,
                                                     const float* __restrict__ PA, int paa, int pab,
                                                     float* __restrict__ out, int coff){
  __shared__ __align__(16) float sh[4][10][68];
  const int tid = threadIdx.x;
  const int w = tid >> 6, o = tid & 63;
  const int p = blockIdx.x*4 + w, b = p >> 13;
  const float aa = PA[paa], ab = PA[pab];

  float wreg[64];
  #pragma unroll
  for (int c=0;c<64;++c) wreg[c] = Wb[c*64 + o];

  const float dc = Dp[(size_t)p*64 + o];

  #pragma unroll
  for (int k=0;k<10;++k){
    int nb = idx[p*10 + k];
    float u = U[((size_t)(b<<13)+nb)*64 + o];
    sh[w][k][o] = preluf(u + dc, aa);
  }
  __syncthreads();

  float mx = -INFINITY;
  #pragma unroll 2
  for (int k=0;k<10;++k){
    float a0=0.f,a1=0.f,a2=0.f,a3=0.f;
    #pragma unroll
    for (int c4=0;c4<16;++c4){
      float4 hv = *(const float4*)&sh[w][k][c4*4];
      a0 = fmaf(hv.x, wreg[c4*4+0], a0);
      a1 = fmaf(hv.y, wreg[c4*4+1], a1);
      a2 = fmaf(hv.z, wreg[c4*4+2], a2);
      a3 = fmaf(hv.w, wreg[c4*4+3], a3);
    }
    float z = (a0+a1)+(a2+a3);
    mx = fmaxf(mx, preluf(z, ab));
  }
  out[(size_t)p*192 + coff + o] = mx;
}

// ---------- single-layer edge conv (conv3), wave-per-point ----------
__global__ __launch_bounds__(256) void edge1w_kernel(const float* __restrict__ U,
                                                     const float* __restrict__ Dp,
                                                     const int* __restrict__ idx,
                                                     const float* __restrict__ PA, int paa,
                                                     float* __restrict__ out, int coff){
  const int tid = threadIdx.x;
  const int w = tid >> 6, o = tid & 63;
  const int p = blockIdx.x*4 + w, b = p >> 13;
  const float aa = PA[paa];
  const float dc = Dp[(size_t)p*64 + o];
  float mx = -INFINITY;
  #pragma unroll
  for (int k=0;k<10;++k){
    int nb = idx[p*10 + k];
    float u = U[((size_t)(b<<13)+nb)*64 + o];
    mx = fmaxf(mx, preluf(u + dc, aa));
  }
  out[(size_t)p*192 + coff + o] = mx;
}

// ---------- tiled fp32 GEMM: C = prelu(A@B [+bias]) ; EPI2: column-max partials ----------
template<int EPI>
__global__ __launch_bounds__(256) void gemm_kernel(const float* __restrict__ A, int lda,
                                                   const float* __restrict__ Bm, int ldb,
                                                   float* __restrict__ C, int ldc,
                                                   const float* __restrict__ bias,
                                                   const float* __restrict__ PA, int pidx,
                                                   int K, int Ntot){
  __shared__ __align__(16) float As[16][132];
  __shared__ __align__(16) float Bs[16][132];
  const int tid = threadIdx.x;
  const int m0 = blockIdx.x*128, n0 = blockIdx.y*128;
  const int tm = tid & 15, tn = tid >> 4;
  float acc[8][8];
  #pragma unroll
  for (int i=0;i<8;++i)
    #pragma unroll
    for (int j=0;j<8;++j) acc[i][j]=0.f;

  for (int k0=0;k0<K;k0+=16) {
    {
      int r = tid >> 2, kq = (tid&3)*4;
      #pragma unroll
      for (int it=0; it<2; ++it) {
        int rr = r + it*64;
        float4 v = *(const float4*)(A + (size_t)(m0+rr)*lda + k0 + kq);
        As[kq+0][rr]=v.x; As[kq+1][rr]=v.y; As[kq+2][rr]=v.z; As[kq+3][rr]=v.w;
      }
    }
    {
      int kk = tid >> 4, c = (tid&15)*8;
      const float* bp = Bm + (size_t)(k0+kk)*ldb + n0 + c;
      *(float4*)&Bs[kk][c]   = *(const float4*)bp;
      *(float4*)&Bs[kk][c+4] = *(const float4*)(bp+4);
    }
    __syncthreads();
    #pragma unroll
    for (int kk=0;kk<16;++kk) {
      float av[8], bv[8];
      *(float4*)&av[0] = *(const float4*)&As[kk][tm*8+0];
      *(float4*)&av[4] = *(const float4*)&As[kk][tm*8+4];
      *(float4*)&bv[0] = *(const float4*)&Bs[kk][tn*8+0];
      *(float4*)&bv[4] = *(const float4*)&Bs[kk][tn*8+4];
      #pragma unroll
      for (int i=0;i<8;++i)
        #pragma unroll
        for (int j=0;j<8;++j)
          acc[i][j] = fmaf(av[i], bv[j], acc[i][j]);
    }
    __syncthreads();
  }
  const float a = PA[pidx];
  if (EPI == 2) {
    #pragma unroll
    for (int j=0;j<8;++j) {
      float m = -INFINITY;
      #pragma unroll
      for (int i=0;i<8;++i) { float v = acc[i][j]; v = v>=0.f? v : a*v; m = fmaxf(m,v); }
      #pragma unroll
      for (int off=1;off<16;off<<=1) m = fmaxf(m, __shfl_xor(m, off));
      if (tm == 0) C[(size_t)blockIdx.x*Ntot + n0 + tn*8 + j] = m;
    }
  } else {
    float bcol[8];
    if (EPI==1) {
      int bb = m0 >> 13;
      #pragma unroll
      for (int j=0;j<8;++j) bcol[j] = bias[bb*256 + n0 + tn*8 + j];
    }
    #pragma unroll
    for (int i=0;i<8;++i) {
      float out[8];
      #pragma unroll
      for (int j=0;j<8;++j) {
        float v = acc[i][j] + (EPI==1 ? bcol[j] : 0.f);
        out[j] = v>=0.f? v : a*v;
      }
      float* cp = C + (size_t)(m0 + tm*8 + i)*ldc + n0 + tn*8;
      *(float4*)cp     = make_float4(out[0],out[1],out[2],out[3]);
      *(float4*)(cp+4) = make_float4(out[4],out[5],out[6],out[7]);
    }
  }
}

__global__ __launch_bounds__(256) void reduce_pmax(const float* __restrict__ pmax,
                                                   float* __restrict__ x5m){
  int t = blockIdx.x*256 + threadIdx.x;
  if (t < 4096) {
    int b = t >> 10, o = t & 1023;
    float m = -INFINITY;
    for (int mt=0; mt<64; ++mt) m = fmaxf(m, pmax[((size_t)(b*64+mt))*1024 + o]);
    x5m[t] = m;
  }
}

__global__ __launch_bounds__(256) void bias7_kernel(const float* __restrict__ x5m,
                                                    const float* __restrict__ W7,
                                                    float* __restrict__ b7){
  int b = blockIdx.x; int o = threadIdx.x;
  float s = 0.f;
  for (int j=0;j<1024;++j) s = fmaf(x5m[b*1024+j], W7[(size_t)(192+j)*256 + o], s);
  b7[b*256+o] = s;
}

__global__ __launch_bounds__(256) void final10_kernel(const float* __restrict__ y3,
                                                      const float* __restrict__ W10,
                                                      const float* __restrict__ PA,
                                                      float* __restrict__ out){
  int p = blockIdx.x*256 + threadIdx.x;
  const float4* r = (const float4*)(y3 + (size_t)p*128);
  float s0=0.f, s1=0.f;
  #pragma unroll
  for (int c4=0;c4<32;++c4){
    float4 v = r[c4];
    s0 = fmaf(v.x, W10[(c4*4+0)*2+0], s0); s1 = fmaf(v.x, W10[(c4*4+0)*2+1], s1);
    s0 = fmaf(v.y, W10[(c4*4+1)*2+0], s0); s1 = fmaf(v.y, W10[(c4*4+1)*2+1], s1);
    s0 = fmaf(v.z, W10[(c4*4+2)*2+0], s0); s1 = fmaf(v.z, W10[(c4*4+2)*2+1], s1);
    s0 = fmaf(v.w, W10[(c4*4+3)*2+0], s0); s1 = fmaf(v.w, W10[(c4*4+3)*2+1], s1);
  }
  float a = PA[9];
  out[p*2+0] = s0>=0.f? s0 : a*s0;
  out[p*2+1] = s1>=0.f? s1 : a*s1;
}

extern "C" void kernel_launch(void* const* d_in, const int* in_sizes, int n_in,
                              void* d_out, int out_size, void* d_ws, size_t ws_size,
                              hipStream_t stream) {
  const float* T   = (const float*)d_in[0];
  const float* W1  = (const float*)d_in[1];
  const float* W2  = (const float*)d_in[2];
  const float* W3  = (const float*)d_in[3];
  const float* W4  = (const float*)d_in[4];
  const float* W5  = (const float*)d_in[5];
  const float* W6  = (const float*)d_in[6];
  const float* W7  = (const float*)d_in[7];
  const float* W8  = (const float*)d_in[8];
  const float* W9  = (const float*)d_in[9];
  const float* W10 = (const float*)d_in[10];
  const float* PA  = (const float*)d_in[11];

  float* ws   = (float*)d_ws;
  float* x0   = ws + 0;                // 131072
  float* sqn0 = ws + 131072;           // 32768
  float* sqn1 = ws + 163840;           // 32768
  float* sqn2 = ws + 196608;           // 32768
  int*   idx0 = (int*)(ws + 229376);   // 327680
  int*   idx1 = (int*)(ws + 557056);   // 327680
  int*   idx2 = (int*)(ws + 884736);   // 327680
  float* xcat = ws + 1212416;          // 6291456  [B,N,192]
  float* pmax = ws + 7503872;          // 262144
  float* x5m  = ws + 7766016;          // 4096
  float* b7   = ws + 7770112;          // 1024
  float* y1   = ws + 7771136;          // 8388608  (aliased: U / knn partials)
  float* y2   = ws + 16159744;         // 8388608  (aliased: D)
  float* y3   = xcat;
  float* U    = y1;
  float* D    = y2;
  float* pd   = y1;                    // [2][32768][10] f32
  int*   pi   = (int*)(y1 + 655360);   // [2][32768][10] i32

  // conv1
  prep0_kernel<<<128, 256, 0, stream>>>(T, x0, sqn0);
  knn4_kernel<<<dim3(64,4,2), 256, 0, stream>>>(x0, sqn0, pd, pi);
  knnmerge_kernel<<<128, 256, 0, stream>>>(pd, pi, idx0);
  prepUD12_kernel<<<128, 256, 0, stream>>>(T, W1, U, D);
  edge2w_kernel<<<8192, 256, 0, stream>>>(U, D, idx0, W2, PA, 0, 1, xcat, 0);

  // conv2
  sqnorm_kernel<<<128, 256, 0, stream>>>(xcat, 0, sqn1);
  knn64_kernel<<<dim3(64,4,2), 256, 0, stream>>>(xcat, 192, 0, sqn1, pd, pi);
  knnmerge_kernel<<<128, 256, 0, stream>>>(pd, pi, idx1);
  prepUD64_kernel<<<128, 256, 0, stream>>>(xcat, 0, W3, U, D);
  edge2w_kernel<<<8192, 256, 0, stream>>>(U, D, idx1, W4, PA, 2, 3, xcat, 64);

  // conv3
  sqnorm_kernel<<<128, 256, 0, stream>>>(xcat, 64, sqn2);
  knn64_kernel<<<dim3(64,4,2), 256, 0, stream>>>(xcat, 192, 64, sqn2, pd, pi);
  knnmerge_kernel<<<128, 256, 0, stream>>>(pd, pi, idx2);
  prepUD64_kernel<<<128, 256, 0, stream>>>(xcat, 64, W5, U, D);
  edge1w_kernel<<<8192, 256, 0, stream>>>(U, D, idx2, PA, 4, xcat, 128);

  // head
  gemm_kernel<2><<<dim3(256,8), 256, 0, stream>>>(xcat, 192, W6, 1024, pmax, 0, nullptr, PA, 5, 192, 1024);
  reduce_pmax<<<16, 256, 0, stream>>>(pmax, x5m);
  bias7_kernel<<<4, 256, 0, stream>>>(x5m, W7, b7);
  gemm_kernel<1><<<dim3(256,2), 256, 0, stream>>>(xcat, 192, W7, 256, y1, 256, b7, PA, 6, 192, 256);
  gemm_kernel<0><<<dim3(256,2), 256, 0, stream>>>(y1, 256, W8, 256, y2, 256, nullptr, PA, 7, 256, 256);
  gemm_kernel<0><<<dim3(256,1), 256, 0, stream>>>(y2, 256, W9, 128, y3, 128, nullptr, PA, 8, 256, 128);
  final10_kernel<<<128, 256, 0, stream>>>(y3, W10, PA, (float*)d_out);
}

// Round 6
// 1725.623 us; speedup vs baseline: 4.5970x; 1.3393x over previous
//
#include <hip/hip_runtime.h>
#include <math.h>

#define NPTS 8192
#define KNNK 10

typedef __attribute__((ext_vector_type(8))) short bf16x8s;
typedef __attribute__((ext_vector_type(4))) float f32x4;

__device__ __forceinline__ float preluf(float v, float a){ return v >= 0.f ? v : a*v; }
__device__ __forceinline__ float4 f4fma(float a, float4 b, float4 c){
  return make_float4(fmaf(a,b.x,c.x), fmaf(a,b.y,c.y), fmaf(a,b.z,c.z), fmaf(a,b.w,c.w));
}

// f64 lex key: double(d) with j OR'd into the 29 zero low-mantissa bits.
// Plain double order == lex-(d,j) for all finite d (j-jitter < 2^-39 rel).
// Body is a no-op for lanes with d >= bd9, so wave-uniform execution is safe.
__device__ __forceinline__ void kinsd(double* bk, float& bd9, float d, int j){
  if (__any(d < bd9)) {
    double t = (double)d;
    t = __longlong_as_double(__double_as_longlong(t) | (unsigned long long)(unsigned)j);
    #pragma unroll
    for (int s=0;s<10;++s){
      double mn = fmin(bk[s], t);
      double mx = fmax(bk[s], t);
      bk[s] = mn; t = mx;
    }
    bd9 = (float)bk[9];   // jitter < 0.5 ulp(f32) -> rounds back to exact d9
  }
}

// split float into bf16 hi/lo (rne); returns packed hi pair, sets lo pair
__device__ __forceinline__ unsigned bfsplit2(float a, float b, unsigned& lo2){
  unsigned ua = __float_as_uint(a), ub = __float_as_uint(b);
  unsigned ha = (ua + 0x7FFFu + ((ua>>16)&1u)) & 0xFFFF0000u;
  unsigned hb = (ub + 0x7FFFu + ((ub>>16)&1u)) & 0xFFFF0000u;
  float ra = a - __uint_as_float(ha);
  float rb = b - __uint_as_float(hb);
  unsigned la = __float_as_uint(ra), lb = __float_as_uint(rb);
  unsigned qa = (la + 0x7FFFu + ((la>>16)&1u)) >> 16;
  unsigned qb = (lb + 0x7FFFu + ((lb>>16)&1u)) & 0xFFFF0000u;
  lo2 = qa | qb;
  return (ha >> 16) | hb;
}

// ---------- prep: x0pad (targets padded to 4ch) + sqnorm ----------
__global__ __launch_bounds__(256) void prep0_kernel(const float* __restrict__ T,
                                                    float* __restrict__ x0,
                                                    float* __restrict__ sqn){
  int p = blockIdx.x*256 + threadIdx.x;
  float t0 = T[p*3+0], t1 = T[p*3+1], t2 = T[p*3+2];
  *(float4*)(x0 + (size_t)p*4) = make_float4(t0,t1,t2,0.f);
  float s = fmaf(t0,t0,0.f); s = fmaf(t1,t1,s); s = fmaf(t2,t2,s); s = fmaf(0.f,0.f,s);
  sqn[p] = s;
}

__global__ __launch_bounds__(256) void sqnorm_kernel(const float* __restrict__ XC, int cin,
                                                     float* __restrict__ sqn){
  int p = blockIdx.x*256 + threadIdx.x;
  const float4* r = (const float4*)(XC + (size_t)p*192 + cin);
  float s = 0.f;
  #pragma unroll
  for (int c4=0;c4<16;++c4){
    float4 v = r[c4];
    s = fmaf(v.x,v.x,s); s = fmaf(v.y,v.y,s); s = fmaf(v.z,v.z,s); s = fmaf(v.w,v.w,s);
  }
  sqn[p] = s;
}

// ---------- KNN for C=64 features: MFMA bf16 hi/lo distance GEMM + f64-key top-10 ----------
__global__ __launch_bounds__(256, 2) void knn64_kernel(const float* __restrict__ X, int ldx, int coff,
                                                       const float* __restrict__ sqn,
                                                       double* __restrict__ pk){
  __shared__ __align__(16) unsigned short xq[2*128*72];  // [hilo][q][72] bf16 bits
  __shared__ __align__(16) unsigned char uni[36864];     // xj bf16 | dch[128][68] f32 | lists f64
  __shared__ float s_x2q[128];
  __shared__ float s_x2j[128];

  unsigned short* xj = (unsigned short*)uni;
  float* dch = (float*)uni;
  double* lst = (double*)uni;                // [128][20]

  const int b   = blockIdx.y;
  const int q0  = blockIdx.x * 128;
  const int jh  = blockIdx.z;
  const int tid = threadIdx.x;
  const int L   = tid & 63;
  const int w   = tid >> 6;
  const int lm  = L & 15;
  const int kg  = L >> 4;
  const int tq  = tid & 127;
  const int th  = tid >> 7;

  const float* Xb = X + (size_t)b * NPTS * ldx + coff;

  #pragma unroll
  for (int s=0;s<8;++s){
    int e = tid + s*256;
    int r = e >> 4, c4 = (e & 15) << 2;
    float4 v = *(const float4*)(Xb + (size_t)(q0+r)*ldx + c4);
    unsigned lo01, lo23;
    unsigned hi01 = bfsplit2(v.x, v.y, lo01);
    unsigned hi23 = bfsplit2(v.z, v.w, lo23);
    uint2 hp; hp.x = hi01; hp.y = hi23;
    uint2 lp; lp.x = lo01; lp.y = lo23;
    *(uint2*)&xq[r*72 + c4]        = hp;
    *(uint2*)&xq[9216 + r*72 + c4] = lp;
  }
  if (tid < 128) s_x2q[tid] = sqn[b*NPTS + q0 + tid];

  double bk[10]; float bd9 = INFINITY;
  #pragma unroll
  for (int u=0;u<10;++u) bk[u] = (double)INFINITY;

  for (int t = 0; t < 32; ++t) {
    const int j0 = jh*4096 + t*128;
    #pragma unroll
    for (int s=0;s<8;++s){
      int e = tid + s*256;
      int r = e >> 4, c4 = (e & 15) << 2;
      float4 v = *(const float4*)(Xb + (size_t)(j0+r)*ldx + c4);
      unsigned lo01, lo23;
      unsigned hi01 = bfsplit2(v.x, v.y, lo01);
      unsigned hi23 = bfsplit2(v.z, v.w, lo23);
      uint2 hp; hp.x = hi01; hp.y = hi23;
      uint2 lp; lp.x = lo01; lp.y = lo23;
      *(uint2*)&xj[r*72 + c4]        = hp;
      *(uint2*)&xj[9216 + r*72 + c4] = lp;
    }
    if (tid < 128) s_x2j[tid] = sqn[b*NPTS + j0 + tid];
    __syncthreads();

    f32x4 acc[2][8];
    #pragma unroll
    for (int mt=0;mt<2;++mt)
      #pragma unroll
      for (int nt=0;nt<8;++nt) acc[mt][nt] = (f32x4){0.f,0.f,0.f,0.f};

    #pragma unroll
    for (int kc=0;kc<2;++kc){
      const int ko = kc*32 + kg*8;
      bf16x8s ah[2], al[2];
      #pragma unroll
      for (int mt=0;mt<2;++mt){
        int q = w*32 + mt*16 + lm;
        ah[mt] = *(const bf16x8s*)&xq[q*72 + ko];
        al[mt] = *(const bf16x8s*)&xq[9216 + q*72 + ko];
      }
      #pragma unroll
      for (int nt=0;nt<8;++nt){
        int n = nt*16 + lm;
        bf16x8s bh = *(const bf16x8s*)&xj[n*72 + ko];
        bf16x8s bl = *(const bf16x8s*)&xj[9216 + n*72 + ko];
        #pragma unroll
        for (int mt=0;mt<2;++mt){
          acc[mt][nt] = __builtin_amdgcn_mfma_f32_16x16x32_bf16(ah[mt], bh, acc[mt][nt], 0,0,0);
          acc[mt][nt] = __builtin_amdgcn_mfma_f32_16x16x32_bf16(ah[mt], bl, acc[mt][nt], 0,0,0);
          acc[mt][nt] = __builtin_amdgcn_mfma_f32_16x16x32_bf16(al[mt], bh, acc[mt][nt], 0,0,0);
        }
      }
    }
    __syncthreads();   // xj reads done; uni becomes dch

    #pragma unroll
    for (int h=0; h<2; ++h) {
      #pragma unroll
      for (int mt=0;mt<2;++mt){
        #pragma unroll
        for (int ntl=0;ntl<4;++ntl){
          int nt = h*4 + ntl;
          f32x4 c = acc[mt][nt];
          int colc = ntl*16 + lm;
          float xj2 = s_x2j[h*64 + colc];
          #pragma unroll
          for (int r=0;r<4;++r){
            int qrow = w*32 + mt*16 + kg*4 + r;
            dch[qrow*68 + colc] = s_x2q[qrow] + xj2 - 2.0f*c[r];
          }
        }
      }
      __syncthreads();
      {
        const int jb0 = j0 + h*64 + th*32;
        #pragma unroll
        for (int c4=0;c4<8;++c4){
          float4 dv = *(const float4*)&dch[tq*68 + th*32 + c4*4];
          int jj = jb0 + c4*4;
          kinsd(bk, bd9, dv.x, jj);
          kinsd(bk, bd9, dv.y, jj+1);
          kinsd(bk, bd9, dv.z, jj+2);
          kinsd(bk, bd9, dv.w, jj+3);
        }
      }
      __syncthreads();
    }
  }

  // in-block merge of 2 per-thread lists per query (f64 key order == lex)
  #pragma unroll
  for (int u=0;u<10;++u) lst[tq*20 + th*10 + u] = bk[u];
  __syncthreads();
  if (tid < 128) {
    const double* row = &lst[tid*20];
    int ia=0, ib=0;
    size_t base = ((size_t)jh*(4*NPTS) + (size_t)b*NPTS + q0 + tid)*10;
    #pragma unroll
    for (int u=0;u<10;++u){
      double ka = row[ia], kb2 = row[10+ib];
      bool ta = ka < kb2;
      pk[base+u] = ta ? ka : kb2;
      ia += ta ? 1 : 0; ib += ta ? 0 : 1;
    }
  }
}

// ---------- KNN for conv1 (C=4, fp32 VALU GEMM, exact self-dist) ----------
__global__ __launch_bounds__(256, 2) void knn4_kernel(const float* __restrict__ X,
                                                      const float* __restrict__ sqn,
                                                      double* __restrict__ pk){
  __shared__ __align__(16) float xqT[4*132];
  __shared__ __align__(16) float uni[10752];   // xjT[4][132] | dch[128][68] | lists f64
  __shared__ float s_x2q[128];
  __shared__ float s_x2j[128];

  const int b   = blockIdx.y;
  const int q0  = blockIdx.x * 128;
  const int jh  = blockIdx.z;
  const int tid = threadIdx.x;
  const int tn  = tid & 15;
  const int tm  = tid >> 4;
  const int tq  = tid & 127;
  const int th  = tid >> 7;

  const float* Xb = X + (size_t)b * NPTS * 4;

  for (int i = tid; i < 128; i += 256) {
    float4 v = *(const float4*)(Xb + (size_t)(q0+i)*4);
    xqT[0*132+i] = v.x; xqT[1*132+i] = v.y; xqT[2*132+i] = v.z; xqT[3*132+i] = v.w;
  }
  if (tid < 128) s_x2q[tid] = sqn[b*NPTS + q0 + tid];

  const int sw  = ((tn>>2)&3) << 2;
  const int bp0 = (tn*8)     ^ sw;
  const int bp1 = (tn*8 + 4) ^ sw;

  double bk[10]; float bd9 = INFINITY;
  #pragma unroll
  for (int u=0;u<10;++u) bk[u] = (double)INFINITY;

  for (int t = 0; t < 32; ++t) {
    const int j0 = jh*4096 + t*128;
    __syncthreads();
    for (int i = tid; i < 128; i += 256) {
      float4 v = *(const float4*)(Xb + (size_t)(j0+i)*4);
      int pj = i ^ (((i>>5)&3) << 2);
      uni[0*132+pj] = v.x; uni[1*132+pj] = v.y; uni[2*132+pj] = v.z; uni[3*132+pj] = v.w;
    }
    if (tid < 128) s_x2j[tid] = sqn[b*NPTS + j0 + tid];
    __syncthreads();

    float acc[8][8];
    #pragma unroll
    for (int i=0;i<8;++i)
      #pragma unroll
      for (int j=0;j<8;++j) acc[i][j] = 0.f;

    #pragma unroll
    for (int kk=0; kk<4; ++kk) {
      float av[8], bv[8];
      *(float4*)&av[0] = *(const float4*)&xqT[kk*132 + tm*8];
      *(float4*)&av[4] = *(const float4*)&xqT[kk*132 + tm*8 + 4];
      *(float4*)&bv[0] = *(const float4*)&uni[kk*132 + bp0];
      *(float4*)&bv[4] = *(const float4*)&uni[kk*132 + bp1];
      #pragma unroll
      for (int i=0;i<8;++i)
        #pragma unroll
        for (int j=0;j<8;++j)
          acc[i][j] = fmaf(av[i], bv[j], acc[i][j]);
    }
    __syncthreads();  // gemm reads done; uni becomes dch[128][68]

    #pragma unroll
    for (int h=0; h<2; ++h) {
      if ((tn>>3) == h) {
        #pragma unroll
        for (int qi=0; qi<8; ++qi) {
          const int row = tm*8 + qi;
          const float xq2 = s_x2q[row];
          float vv[8];
          #pragma unroll
          for (int u=0;u<8;++u)
            vv[u] = xq2 + s_x2j[tn*8 + u] - 2.f*acc[qi][u];
          *(float4*)&uni[row*68 + (tn&7)*8]     = make_float4(vv[0],vv[1],vv[2],vv[3]);
          *(float4*)&uni[row*68 + (tn&7)*8 + 4] = make_float4(vv[4],vv[5],vv[6],vv[7]);
        }
      }
      __syncthreads();
      {
        const int jb0 = j0 + h*64 + th*32;
        #pragma unroll
        for (int c4=0;c4<8;++c4){
          float4 dv = *(const float4*)&uni[tq*68 + th*32 + c4*4];
          int jj = jb0 + c4*4;
          kinsd(bk, bd9, dv.x, jj);
          kinsd(bk, bd9, dv.y, jj+1);
          kinsd(bk, bd9, dv.z, jj+2);
          kinsd(bk, bd9, dv.w, jj+3);
        }
      }
      __syncthreads();
    }
  }

  double* lst = (double*)uni;    // [128][20]
  #pragma unroll
  for (int u=0;u<10;++u) lst[tq*20 + th*10 + u] = bk[u];
  __syncthreads();
  if (tid < 128) {
    const double* row = &lst[tid*20];
    int ia=0, ib=0;
    size_t base = ((size_t)jh*(4*NPTS) + (size_t)b*NPTS + q0 + tid)*10;
    #pragma unroll
    for (int u=0;u<10;++u){
      double ka = row[ia], kb2 = row[10+ib];
      bool ta = ka < kb2;
      pk[base+u] = ta ? ka : kb2;
      ia += ta ? 1 : 0; ib += ta ? 0 : 1;
    }
  }
}

// ---------- merge the 2 j-half partial f64-key lists -> final idx ----------
__global__ __launch_bounds__(256) void knnmerge_kernel(const double* __restrict__ pk,
                                                       int* __restrict__ idxout){
  int p = blockIdx.x*256 + threadIdx.x;   // 0..32767
  const double* A = pk + (size_t)p*10;
  const double* B = pk + (size_t)(4*NPTS)*10 + (size_t)p*10;
  int ia=0, ib=0;
  int* op = idxout + (size_t)p*10;
  #pragma unroll
  for (int u=0;u<10;++u){
    double ka = A[ia], kb = B[ib];
    bool t = ka < kb;
    op[u] = (int)(__double_as_longlong(t ? ka : kb) & 8191LL);
    ia += t ? 1 : 0; ib += t ? 0 : 1;
  }
}

// ---------- prep U/D for 64-ch edge conv ----------
__global__ __launch_bounds__(256) void prepUD64_kernel(const float* __restrict__ XC, int cin,
                                                       const float* __restrict__ W,
                                                       float* __restrict__ U,
                                                       float* __restrict__ D){
  int p = blockIdx.x*256 + threadIdx.x;
  float x[64];
  {
    const float4* xr = (const float4*)(XC + (size_t)p*192 + cin);
    #pragma unroll
    for (int c4=0;c4<16;++c4){
      float4 v = xr[c4];
      x[c4*4]=v.x; x[c4*4+1]=v.y; x[c4*4+2]=v.z; x[c4*4+3]=v.w;
    }
  }
  const float4* W4 = (const float4*)W;
  float4 z[16];
  #pragma unroll
  for (int o=0;o<16;++o) z[o] = make_float4(0,0,0,0);
  #pragma unroll
  for (int c=0;c<64;++c) {
    const float xc = x[c];
    #pragma unroll
    for (int o=0;o<16;++o) z[o] = f4fma(xc, W4[c*16+o], z[o]);
  }
  float4* up = (float4*)(U + (size_t)p*64);
  #pragma unroll
  for (int o=0;o<16;++o) up[o] = z[o];
  #pragma unroll
  for (int o=0;o<16;++o) z[o] = make_float4(0,0,0,0);
  #pragma unroll
  for (int c=0;c<64;++c) {
    const float xc = x[c];
    #pragma unroll
    for (int o=0;o<16;++o) {
      float4 wt = W4[c*16+o], wb = W4[(64+c)*16+o];
      float4 wd = make_float4(wb.x-wt.x, wb.y-wt.y, wb.z-wt.z, wb.w-wt.w);
      z[o] = f4fma(xc, wd, z[o]);
    }
  }
  float4* dp = (float4*)(D + (size_t)p*64);
  #pragma unroll
  for (int o=0;o<16;++o) dp[o] = z[o];
}

// ---------- prep U/D for conv1 ----------
__global__ __launch_bounds__(256) void prepUD12_kernel(const float* __restrict__ T,
                                                       const float* __restrict__ W1,
                                                       float* __restrict__ U,
                                                       float* __restrict__ D){
  int p = blockIdx.x*256 + threadIdx.x;
  float t[3] = {T[p*3+0], T[p*3+1], T[p*3+2]};
  const float4* W = (const float4*)W1;
  float4 u[16], q[16];
  #pragma unroll
  for (int o=0;o<16;++o){ u[o]=make_float4(0,0,0,0); q[o]=make_float4(0,0,0,0); }
  #pragma unroll
  for (int c=0;c<3;++c){
    const float tc = t[c];
    #pragma unroll
    for (int o=0;o<16;++o){
      float4 ws  = W[c*16+o],     ws2 = W[(c+3)*16+o];
      float4 wq  = W[(c+6)*16+o], wq2 = W[(c+9)*16+o];
      u[o] = f4fma(tc, make_float4(ws.x+ws2.x, ws.y+ws2.y, ws.z+ws2.z, ws.w+ws2.w), u[o]);
      q[o] = f4fma(tc, make_float4(wq.x+wq2.x, wq.y+wq2.y, wq.z+wq2.z, wq.w+wq2.w), q[o]);
    }
  }
  float4* up = (float4*)(U + (size_t)p*64);
  float4* dp = (float4*)(D + (size_t)p*64);
  #pragma unroll
  for (int o=0;o<16;++o){
    up[o] = u[o];
    dp[o] = make_float4(q[o].x-u[o].x, q[o].y-u[o].y, q[o].z-u[o].z, q[o].w-u[o].w);
  }
}

// ---------- two-layer edge conv, wave-per-point: lane = out-channel ----------
__global__ __launch_bounds__(256) void edge2w_kernel(const float* __restrict__ U,
                                                     const float* __restrict__ Dp,
                                                     const int* __restrict__ idx,
                                                     const float* __restrict__ Wb,
                                                     const float* __restrict__ PA, int paa, int pab,
                                                     float* __restrict__ out, int coff){
  __shared__ __align__(16) float sh[4][10][68];
  const int tid = threadIdx.x;
  const int w = tid >> 6, o = tid & 63;
  const int p = blockIdx.x*4 + w, b = p >> 13;
  const float aa = PA[paa], ab = PA[pab];

  float wreg[64];
  #pragma unroll
  for (int c=0;c<64;++c) wreg[c] = Wb[c*64 + o];

  const float dc = Dp[(size_t)p*64 + o];

  #pragma unroll
  for (int k=0;k<10;++k){
    int nb = idx[p*10 + k];
    float u = U[((size_t)(b<<13)+nb)*64 + o];
    sh[w][k][o] = preluf(u + dc, aa);
  }
  __syncthreads();

  float mx = -INFINITY;
  #pragma unroll 2
  for (int k=0;k<10;++k){
    float a0=0.f,a1=0.f,a2=0.f,a3=0.f;
    #pragma unroll
    for (int c4=0;c4<16;++c4){
      float4 hv = *(const float4*)&sh[w][k][c4*4];
      a0 = fmaf(hv.x, wreg[c4*4+0], a0);
      a1 = fmaf(hv.y, wreg[c4*4+1], a1);
      a2 = fmaf(hv.z, wreg[c4*4+2], a2);
      a3 = fmaf(hv.w, wreg[c4*4+3], a3);
    }
    float z = (a0+a1)+(a2+a3);
    mx = fmaxf(mx, preluf(z, ab));
  }
  out[(size_t)p*192 + coff + o] = mx;
}

// ---------- single-layer edge conv (conv3), wave-per-point ----------
__global__ __launch_bounds__(256) void edge1w_kernel(const float* __restrict__ U,
                                                     const float* __restrict__ Dp,
                                                     const int* __restrict__ idx,
                                                     const float* __restrict__ PA, int paa,
                                                     float* __restrict__ out, int coff){
  const int tid = threadIdx.x;
  const int w = tid >> 6, o = tid & 63;
  const int p = blockIdx.x*4 + w, b = p >> 13;
  const float aa = PA[paa];
  const float dc = Dp[(size_t)p*64 + o];
  float mx = -INFINITY;
  #pragma unroll
  for (int k=0;k<10;++k){
    int nb = idx[p*10 + k];
    float u = U[((size_t)(b<<13)+nb)*64 + o];
    mx = fmaxf(mx, preluf(u + dc, aa));
  }
  out[(size_t)p*192 + coff + o] = mx;
}

// ---------- weight prep: W[K][N] fp32 -> Wh/Wl[N][K] bf16 bits (transposed hi/lo) ----------
__global__ __launch_bounds__(256) void prepW_kernel(const float* __restrict__ W, int K, int N,
                                                    unsigned short* __restrict__ Wh,
                                                    unsigned short* __restrict__ Wl){
  int k = blockIdx.x;
  for (int n = threadIdx.x; n < N; n += 256){
    float v = W[(size_t)k*N + n];
    unsigned ua = __float_as_uint(v);
    unsigned h = (ua + 0x7FFFu + ((ua>>16)&1u)) & 0xFFFF0000u;
    float r = v - __uint_as_float(h);
    unsigned ub = __float_as_uint(r);
    unsigned l = (ub + 0x7FFFu + ((ub>>16)&1u)) >> 16;
    Wh[(size_t)n*K + k] = (unsigned short)(h >> 16);
    Wl[(size_t)n*K + k] = (unsigned short)l;
  }
}

// ---------- MFMA bf16 hi/lo GEMM: C = prelu(A@W [+bias]); EPI2: colmax partials ----------
// block 256 (4 waves), tile 128m x 128n, K-chunks of 64 (K multiple of 64).
template<int EPI>   // 0: prelu->store, 1: +bias prelu->store, 2: prelu->colmax partial
__global__ __launch_bounds__(256, 2) void mgemm_kernel(const float* __restrict__ A, int lda,
                                                       const unsigned short* __restrict__ WhT,
                                                       const unsigned short* __restrict__ WlT,
                                                       int K,
                                                       float* __restrict__ C, int ldc,
                                                       const float* __restrict__ bias,
                                                       const float* __restrict__ PA, int pidx,
                                                       int Ntot){
  __shared__ __align__(16) unsigned char smem[73728];
  unsigned short* sa = (unsigned short*)smem;            // hi at 0, lo at +9216 ushorts
  unsigned short* sb = (unsigned short*)(smem + 36864);
  float* cst = (float*)smem;                             // epilogue [128][132]

  const int tid = threadIdx.x;
  const int m0 = blockIdx.x*128, n0 = blockIdx.y*128;
  const int L = tid & 63, w = tid >> 6;
  const int lm = L & 15, kg = L >> 4;

  f32x4 acc[2][8];
  #pragma unroll
  for (int mt=0;mt<2;++mt)
    #pragma unroll
    for (int nt=0;nt<8;++nt) acc[mt][nt] = (f32x4){0.f,0.f,0.f,0.f};

  for (int c0 = 0; c0 < K; c0 += 64) {
    __syncthreads();
    // stage A chunk (fp32 -> bf16 hi/lo), 128 rows x 64 k
    #pragma unroll
    for (int s=0;s<8;++s){
      int e = tid + s*256;
      int r = e >> 4, kq = (e & 15) << 2;
      float4 v = *(const float4*)(A + (size_t)(m0+r)*lda + c0 + kq);
      unsigned lo01, lo23;
      unsigned hi01 = bfsplit2(v.x, v.y, lo01);
      unsigned hi23 = bfsplit2(v.z, v.w, lo23);
      uint2 hp; hp.x = hi01; hp.y = hi23;
      uint2 lp; lp.x = lo01; lp.y = lo23;
      *(uint2*)&sa[r*72 + kq]        = hp;
      *(uint2*)&sa[9216 + r*72 + kq] = lp;
    }
    // stage W chunk (already split/transposed): 128 cols x 64 k
    #pragma unroll
    for (int s=0;s<4;++s){
      int e = tid + s*256;
      int col = e >> 3, ko = (e & 7) << 3;
      *(uint4*)&sb[col*72 + ko]        = *(const uint4*)&WhT[(size_t)(n0+col)*K + c0 + ko];
      *(uint4*)&sb[9216 + col*72 + ko] = *(const uint4*)&WlT[(size_t)(n0+col)*K + c0 + ko];
    }
    __syncthreads();

    #pragma unroll
    for (int kc=0;kc<2;++kc){
      const int ko = kc*32 + kg*8;
      bf16x8s ah[2], al[2];
      #pragma unroll
      for (int mt=0;mt<2;++mt){
        int q = w*32 + mt*16 + lm;
        ah[mt] = *(const bf16x8s*)&sa[q*72 + ko];
        al[mt] = *(const bf16x8s*)&sa[9216 + q*72 + ko];
      }
      #pragma unroll
      for (int nt=0;nt<8;++nt){
        int n = nt*16 + lm;
        bf16x8s bh = *(const bf16x8s*)&sb[n*72 + ko];
        bf16x8s bl = *(const bf16x8s*)&sb[9216 + n*72 + ko];
        #pragma unroll
        for (int mt=0;mt<2;++mt){
          acc[mt][nt] = __builtin_amdgcn_mfma_f32_16x16x32_bf16(ah[mt], bh, acc[mt][nt], 0,0,0);
          acc[mt][nt] = __builtin_amdgcn_mfma_f32_16x16x32_bf16(ah[mt], bl, acc[mt][nt], 0,0,0);
          acc[mt][nt] = __builtin_amdgcn_mfma_f32_16x16x32_bf16(al[mt], bh, acc[mt][nt], 0,0,0);
        }
      }
    }
  }
  __syncthreads();   // all LDS reads done before epilogue reuse

  const float a = PA[pidx];
  if (EPI == 2) {
    #pragma unroll
    for (int nt=0;nt<8;++nt){
      f32x4 c0v = acc[0][nt], c1v = acc[1][nt];
      float m = -INFINITY;
      #pragma unroll
      for (int r=0;r<4;++r){ m = fmaxf(m, preluf(c0v[r], a)); m = fmaxf(m, preluf(c1v[r], a)); }
      m = fmaxf(m, __shfl_xor(m, 16));
      m = fmaxf(m, __shfl_xor(m, 32));
      if (kg == 0) cst[w*128 + nt*16 + lm] = m;
    }
    __syncthreads();
    if (tid < 128){
      float m = fmaxf(fmaxf(cst[tid], cst[128+tid]), fmaxf(cst[256+tid], cst[384+tid]));
      C[(size_t)blockIdx.x*Ntot + n0 + tid] = m;
    }
  } else {
    float bc[8];
    if (EPI == 1){
      int bb = m0 >> 13;
      #pragma unroll
      for (int nt=0;nt<8;++nt) bc[nt] = bias[bb*256 + n0 + nt*16 + lm];
    }
    #pragma unroll
    for (int mt=0;mt<2;++mt){
      #pragma unroll
      for (int nt=0;nt<8;++nt){
        f32x4 c = acc[mt][nt];
        int col = nt*16 + lm;
        #pragma unroll
        for (int r=0;r<4;++r){
          int row = w*32 + mt*16 + kg*4 + r;
          float v = c[r] + (EPI==1 ? bc[nt] : 0.f);
          cst[row*132 + col] = preluf(v, a);
        }
      }
    }
    __syncthreads();
    const int tm = tid & 15, tn = tid >> 4;
    #pragma unroll
    for (int i=0;i<8;++i){
      int row = tm*8 + i;
      float4 v0 = *(const float4*)&cst[row*132 + tn*8];
      float4 v1 = *(const float4*)&cst[row*132 + tn*8 + 4];
      float* cp = C + (size_t)(m0 + row)*ldc + n0 + tn*8;
      *(float4*)cp     = v0;
      *(float4*)(cp+4) = v1;
    }
  }
}

__global__ __launch_bounds__(256) void reduce_pmax(const float* __restrict__ pmax,
                                                   float* __restrict__ x5m){
  int t = blockIdx.x*256 + threadIdx.x;
  if (t < 4096) {
    int b = t >> 10, o = t & 1023;
    float m = -INFINITY;
    for (int mt=0; mt<64; ++mt) m = fmaxf(m, pmax[((size_t)(b*64+mt))*1024 + o]);
    x5m[t] = m;
  }
}

__global__ __launch_bounds__(256) void bias7_kernel(const float* __restrict__ x5m,
                                                    const float* __restrict__ W7,
                                                    float* __restrict__ b7){
  int b = blockIdx.x; int o = threadIdx.x;
  float s = 0.f;
  for (int j=0;j<1024;++j) s = fmaf(x5m[b*1024+j], W7[(size_t)(192+j)*256 + o], s);
  b7[b*256+o] = s;
}

__global__ __launch_bounds__(256) void final10_kernel(const float* __restrict__ y3,
                                                      const float* __restrict__ W10,
                                                      const float* __restrict__ PA,
                                                      float* __restrict__ out){
  int p = blockIdx.x*256 + threadIdx.x;
  const float4* r = (const float4*)(y3 + (size_t)p*128);
  float s0=0.f, s1=0.f;
  #pragma unroll
  for (int c4=0;c4<32;++c4){
    float4 v = r[c4];
    s0 = fmaf(v.x, W10[(c4*4+0)*2+0], s0); s1 = fmaf(v.x, W10[(c4*4+0)*2+1], s1);
    s0 = fmaf(v.y, W10[(c4*4+1)*2+0], s0); s1 = fmaf(v.y, W10[(c4*4+1)*2+1], s1);
    s0 = fmaf(v.z, W10[(c4*4+2)*2+0], s0); s1 = fmaf(v.z, W10[(c4*4+2)*2+1], s1);
    s0 = fmaf(v.w, W10[(c4*4+3)*2+0], s0); s1 = fmaf(v.w, W10[(c4*4+3)*2+1], s1);
  }
  float a = PA[9];
  out[p*2+0] = s0>=0.f? s0 : a*s0;
  out[p*2+1] = s1>=0.f? s1 : a*s1;
}

extern "C" void kernel_launch(void* const* d_in, const int* in_sizes, int n_in,
                              void* d_out, int out_size, void* d_ws, size_t ws_size,
                              hipStream_t stream) {
  const float* T   = (const float*)d_in[0];
  const float* W1  = (const float*)d_in[1];
  const float* W2  = (const float*)d_in[2];
  const float* W3  = (const float*)d_in[3];
  const float* W4  = (const float*)d_in[4];
  const float* W5  = (const float*)d_in[5];
  const float* W6  = (const float*)d_in[6];
  const float* W7  = (const float*)d_in[7];
  const float* W8  = (const float*)d_in[8];
  const float* W9  = (const float*)d_in[9];
  const float* W10 = (const float*)d_in[10];
  const float* PA  = (const float*)d_in[11];

  float* ws   = (float*)d_ws;
  float* x0   = ws + 0;                // 131072
  float* sqn0 = ws + 131072;           // 32768
  float* sqn1 = ws + 163840;           // 32768
  float* sqn2 = ws + 196608;           // 32768
  int*   idx0 = (int*)(ws + 229376);   // 327680
  int*   idx1 = (int*)(ws + 557056);   // 327680
  int*   idx2 = (int*)(ws + 884736);   // 327680
  float* xcat = ws + 1212416;          // 6291456  [B,N,192]
  float* pmax = ws + 7503872;          // 262144
  float* x5m  = ws + 7766016;          // 4096
  float* b7   = ws + 7770112;          // 1024
  float* y1   = ws + 7771136;          // 8388608  (aliased: U / knn f64 partials)
  float* y2   = ws + 16159744;         // 8388608  (aliased: D)
  float* y3   = xcat;
  float* U    = y1;
  float* D    = y2;
  double* pk  = (double*)y1;           // [2][32768][10] f64 keys = 5.24 MB

  // split/transposed weights: reuse idx region (dead after edge1w)
  unsigned short* wsc = (unsigned short*)(ws + 229376);
  unsigned short* Wh6 = wsc;                 // 196608
  unsigned short* Wl6 = wsc + 196608;
  unsigned short* Wh7 = wsc + 393216;        // 49152
  unsigned short* Wl7 = wsc + 442368;
  unsigned short* Wh8 = wsc + 491520;        // 65536
  unsigned short* Wl8 = wsc + 557056;
  unsigned short* Wh9 = wsc + 622592;        // 32768
  unsigned short* Wl9 = wsc + 655360;        // end 688128 ushorts <= idx region

  // conv1
  prep0_kernel<<<128, 256, 0, stream>>>(T, x0, sqn0);
  knn4_kernel<<<dim3(64,4,2), 256, 0, stream>>>(x0, sqn0, pk);
  knnmerge_kernel<<<128, 256, 0, stream>>>(pk, idx0);
  prepUD12_kernel<<<128, 256, 0, stream>>>(T, W1, U, D);
  edge2w_kernel<<<8192, 256, 0, stream>>>(U, D, idx0, W2, PA, 0, 1, xcat, 0);

  // conv2
  sqnorm_kernel<<<128, 256, 0, stream>>>(xcat, 0, sqn1);
  knn64_kernel<<<dim3(64,4,2), 256, 0, stream>>>(xcat, 192, 0, sqn1, pk);
  knnmerge_kernel<<<128, 256, 0, stream>>>(pk, idx1);
  prepUD64_kernel<<<128, 256, 0, stream>>>(xcat, 0, W3, U, D);
  edge2w_kernel<<<8192, 256, 0, stream>>>(U, D, idx1, W4, PA, 2, 3, xcat, 64);

  // conv3
  sqnorm_kernel<<<128, 256, 0, stream>>>(xcat, 64, sqn2);
  knn64_kernel<<<dim3(64,4,2), 256, 0, stream>>>(xcat, 192, 64, sqn2, pk);
  knnmerge_kernel<<<128, 256, 0, stream>>>(pk, idx2);
  prepUD64_kernel<<<128, 256, 0, stream>>>(xcat, 64, W5, U, D);
  edge1w_kernel<<<8192, 256, 0, stream>>>(U, D, idx2, PA, 4, xcat, 128);

  // head weights -> bf16 hi/lo transposed (idx region now dead)
  prepW_kernel<<<192, 256, 0, stream>>>(W6, 192, 1024, Wh6, Wl6);
  prepW_kernel<<<192, 256, 0, stream>>>(W7, 192, 256,  Wh7, Wl7);
  prepW_kernel<<<256, 256, 0, stream>>>(W8, 256, 256,  Wh8, Wl8);
  prepW_kernel<<<256, 256, 0, stream>>>(W9, 256, 128,  Wh9, Wl9);

  // head
  mgemm_kernel<2><<<dim3(256,8), 256, 0, stream>>>(xcat, 192, Wh6, Wl6, 192, pmax, 0, nullptr, PA, 5, 1024);
  reduce_pmax<<<16, 256, 0, stream>>>(pmax, x5m);
  bias7_kernel<<<4, 256, 0, stream>>>(x5m, W7, b7);
  mgemm_kernel<1><<<dim3(256,2), 256, 0, stream>>>(xcat, 192, Wh7, Wl7, 192, y1, 256, b7, PA, 6, 0);
  mgemm_kernel<0><<<dim3(256,2), 256, 0, stream>>>(y1, 256, Wh8, Wl8, 256, y2, 256, nullptr, PA, 7, 0);
  mgemm_kernel<0><<<dim3(256,1), 256, 0, stream>>>(y2, 256, Wh9, Wl9, 256, y3, 128, nullptr, PA, 8, 0);
  final10_kernel<<<128, 256, 0, stream>>>(y3, W10, PA, (float*)d_out);
}